// Round 11
// baseline (1991.770 us; speedup 1.0000x reference)
//
#include <hip/hip_runtime.h>
#include <hip/hip_cooperative_groups.h>

namespace cg = cooperative_groups;

#define TPB 512
#define NWG 16

__device__ __forceinline__ float gload(const float* p) {
  return __hip_atomic_load(p, __ATOMIC_RELAXED, __HIP_MEMORY_SCOPE_AGENT);
}

__device__ __forceinline__ float4 gload4(const float* p) {
  float4 r;
  asm volatile("global_load_dwordx4 %0, %1, off sc0 sc1\n\ts_waitcnt vmcnt(0)"
               : "=&v"(r) : "v"(p) : "memory");
  return r;
}

// 64B batched agent-coherent load: 4 dwordx4 issued back-to-back, ONE waitcnt.
__device__ __forceinline__ void gload4x4(const float* p, float4& r0, float4& r1,
                                         float4& r2, float4& r3) {
  asm volatile(
      "global_load_dwordx4 %0, %4, off sc0 sc1\n\t"
      "global_load_dwordx4 %1, %4, off offset:16 sc0 sc1\n\t"
      "global_load_dwordx4 %2, %4, off offset:32 sc0 sc1\n\t"
      "global_load_dwordx4 %3, %4, off offset:48 sc0 sc1\n\t"
      "s_waitcnt vmcnt(0)"
      : "=&v"(r0), "=&v"(r1), "=&v"(r2), "=&v"(r3)
      : "v"(p) : "memory");
}

// ---------------- block-wide reductions (512 threads = 8 waves) ----------------
__device__ __forceinline__ float blk_reduce_max(float v, float* sred, int tid) {
#pragma unroll
  for (int o = 32; o > 0; o >>= 1) v = fmaxf(v, __shfl_down(v, o));
  if ((tid & 63) == 0) sred[tid >> 6] = v;
  __syncthreads();
  if (tid == 0) {
    float m = sred[0];
#pragma unroll
    for (int w = 1; w < TPB / 64; ++w) m = fmaxf(m, sred[w]);
    sred[0] = m;
  }
  __syncthreads();
  const float r = sred[0];
  __syncthreads();
  return r;
}

__device__ __forceinline__ float blk_reduce_sum(float v, float* sred, int tid) {
#pragma unroll
  for (int o = 32; o > 0; o >>= 1) v += __shfl_down(v, o);
  if ((tid & 63) == 0) sred[tid >> 6] = v;
  __syncthreads();
  if (tid == 0) {
    float m = sred[0];
#pragma unroll
    for (int w = 1; w < TPB / 64; ++w) m += sred[w];
    sred[0] = m;
  }
  __syncthreads();
  const float r = sred[0];
  __syncthreads();
  return r;
}

__device__ __forceinline__ float dot_f4(const float* __restrict__ a,
                                        const float* __restrict__ b, int n4) {
  float acc = 0.f;
#pragma unroll 8
  for (int c = 0; c < n4; ++c) {
    const float4 x = ((const float4*)a)[c];
    const float4 y = ((const float4*)b)[c];
    acc = fmaf(x.x, y.x, fmaf(x.y, y.y, fmaf(x.z, y.z, fmaf(x.w, y.w, acc))));
  }
  return acc;
}

// ================= NEW: one-exchange cooperative kernel =================
// Each WG owns V rows [8w,8w+8) persistently in LDS. Per iter: H-slice = Vown@F
// -> ONE grid.sync -> stage H_u + own H8 cols -> replicated Quu/Qxu/q/Newton ->
// distributed K/Vn/vn. Convergence decided with 1-iter lag (uniform).
__global__ __launch_bounds__(TPB) void lqr_h(
    const float* __restrict__ Fg,   // [128][192]
    const float* __restrict__ fg,   // [128]
    const float* __restrict__ Cg,   // [192][192]
    const float* __restrict__ cgv,  // [192]
    float* __restrict__ out,
    float* __restrict__ ws, int T)
{
  cg::grid_group grid = cg::this_grid();
  const int tid = threadIdx.x;
  const int w = blockIdx.x;
  const int ITCAP = 24;

  __shared__ __align__(16) float pool[33128];
  float* const sVown = pool;             // [8][132]
  float* const sHu   = pool + 1056;      // [128][68]
  float* const sH8T  = pool + 9760;      // [8][132]   H[:, own 8 x-cols]^T
  float* const sQXU  = pool + 10816;     // [128][68]
  float* const sQUU  = pool + 19520;     // [64][68]
  float* const sX    = pool + 23872;     // [64][68]   warm inverse
  float* const sT1   = pool + 28224;     // [64][68]   Newton scratch / sM overlay
  float* const sM    = sT1;              // [8][68]
  float* const svown = pool + 32576;     // [8]
  float* const szf   = pool + 32584;     // [128]
  float* const sq    = pool + 32712;     // [192]
  float* const sk    = pool + 32904;     // [64]
  float* const sf    = pool + 32968;     // [128]
  float* const sred  = pool + 33096;     // [16]
  float* const sS    = pool + 33112;     // [8]
  float* const spz   = pool + 33120;     // [4]

  float* const Hg   = ws + 16;           // [128][192]
  float* const zg   = Hg + 24576;        // [128]
  float* const fvfP = zg + 128;          // [16]
  float* const fvP  = fvfP + 16;         // [16]
  float* const convA= fvP + 16;          // [64]
  float* const sentB= convA + 64;        // [16]

  const size_t okOff = (size_t)T * 8192;
  const size_t oVOff = okOff + (size_t)T * 64;
  const size_t ovOff = oVOff + (size_t)T * 16384;
  const size_t ocOff = ovOff + (size_t)T * 128;

  // ---- init (all local)
  if (tid < 128) sf[tid] = fg[tid];
  for (int idx = tid; idx < 8 * 128; idx += TPB) {
    const int r = idx >> 7, j = idx & 127;
    sVown[r * 132 + j] = Cg[(8 * w + r) * 192 + j];
  }
  if (tid < 8) svown[tid] = cgv[8 * w + tid];
  if (tid == 0) {
    sS[0] = 0.f; sS[1] = 0.f; sS[4] = 0.f; sS[5] = 0.85f; sS[6] = 1e30f;
    sS[7] = 0.f; spz[0] = 0.f; spz[1] = 0.f;
  }
  __syncthreads();

  int Sdone = T;
  bool converged = false;

  for (int it = 0; it < ITCAP; ++it) {
    const int rrow = T - 1 - it;

    // ===== local pre-sync: z slice + partials, H slice =====
    {
      float zp1 = 0.f, zp2 = 0.f;
      if (tid < 8) {
        const float zv = dot_f4(&sVown[tid * 132], sf, 32) + svown[tid];
        zg[8 * w + tid] = zv;
        const float fk = sf[8 * w + tid];
        zp1 = fk * (zv - svown[tid]);
        zp2 = fk * svown[tid];
      }
      zp1 += __shfl_down(zp1, 4); zp1 += __shfl_down(zp1, 2); zp1 += __shfl_down(zp1, 1);
      zp2 += __shfl_down(zp2, 4); zp2 += __shfl_down(zp2, 2); zp2 += __shfl_down(zp2, 1);
      if (tid == 0) { fvfP[w] = zp1; fvP[w] = zp2; }
    }
    {  // H[8w+r][j0..j0+2] = Vown[r] . F[:,j]
      const int r = tid >> 6, j0 = (tid & 63) * 3;
      const float* vrow = &sVown[r * 132];
      float h0 = 0.f, h1 = 0.f, h2 = 0.f;
      for (int m4 = 0; m4 < 32; ++m4) {
        const float4 v4 = *(const float4*)&vrow[m4 * 4];
        const float vv[4] = {v4.x, v4.y, v4.z, v4.w};
#pragma unroll
        for (int e = 0; e < 4; ++e) {
          const float* fr = &Fg[(m4 * 4 + e) * 192 + j0];
          h0 = fmaf(vv[e], fr[0], h0);
          h1 = fmaf(vv[e], fr[1], h1);
          h2 = fmaf(vv[e], fr[2], h2);
        }
      }
      float* hr = &Hg[(size_t)(8 * w + (tid >> 6)) * 192 + j0];
      hr[0] = h0; hr[1] = h1; hr[2] = h2;
    }
    __syncthreads();
    if (tid == 0) sentB[w] = (float)(it * 64 + w + 1);
    __threadfence();
    grid.sync();   // ---- the ONE exchange point ----

    // sentinel verify + lagged convergence decision (conv from it-1)
    if (tid < NWG) {
      if (gload(&sentB[tid]) != (float)(it * 64 + tid + 1)) spz[0] = 1.f;
    }
    if (it >= 1 && tid < 16) {
      float c0 = gload(&convA[tid]), c1 = gload(&convA[16 + tid]),
            c2 = gload(&convA[32 + tid]), c3 = gload(&convA[48 + tid]);
#pragma unroll
      for (int o = 8; o > 0; o >>= 1) {
        c0 = fmaxf(c0, __shfl_down(c0, o));
        c1 = fmaxf(c1, __shfl_down(c1, o));
        c2 = fmaxf(c2, __shfl_down(c2, o));
        c3 = fmaxf(c3, __shfl_down(c3, o));
      }
      if (tid == 0)
        spz[1] = ((it - 1) >= 3 && c0 <= 2e-3f * c1 &&
                  c2 <= 4e-3f * fmaxf(1.f, c3) && sS[7] != 0.f) ? 1.f : 0.f;
    }
    __syncthreads();
    if (spz[0] != 0.f) break;
    if (it >= 1 && spz[1] != 0.f) { Sdone = it; converged = true; break; }

    // ===== stage: H_u (batched 64B), own H8 cols, z, partial sums =====
    {
      const int k = tid >> 2, u16 = tid & 3;
      float4 r0, r1, r2, r3;
      gload4x4(&Hg[(size_t)k * 192 + 128 + u16 * 16], r0, r1, r2, r3);
      float* d = &sHu[k * 68 + u16 * 16];
      *(float4*)&d[0] = r0; *(float4*)&d[4] = r1;
      *(float4*)&d[8] = r2; *(float4*)&d[12] = r3;
    }
    if (tid < 256) {
      const int k = tid >> 1, c4 = tid & 1;
      const float4 h = gload4(&Hg[(size_t)k * 192 + 8 * w + c4 * 4]);
      sH8T[(c4 * 4 + 0) * 132 + k] = h.x;
      sH8T[(c4 * 4 + 1) * 132 + k] = h.y;
      sH8T[(c4 * 4 + 2) * 132 + k] = h.z;
      sH8T[(c4 * 4 + 3) * 132 + k] = h.w;
    }
    if (tid < 128) szf[tid] = gload(&zg[tid]);
    {
      float a = 0.f, b = 0.f;
      if (tid < 16) { a = gload(&fvfP[tid]); b = gload(&fvP[tid]); }
      a += __shfl_down(a, 8); a += __shfl_down(a, 4);
      a += __shfl_down(a, 2); a += __shfl_down(a, 1);
      b += __shfl_down(b, 8); b += __shfl_down(b, 4);
      b += __shfl_down(b, 2); b += __shfl_down(b, 1);
      if (tid == 0) { sS[2] = a; sS[3] = b; }
    }
    __syncthreads();

    // ===== replicated: q, Quu, Qxu =====
    if (tid < 192) {
      float qa = cgv[tid];
#pragma unroll 4
      for (int k = 0; k < 128; ++k) qa = fmaf(Fg[k * 192 + tid], szf[k], qa);
      sq[tid] = qa;
    }
    {  // Quu[a][u0..u0+7]
      const int a = tid >> 3, u0 = (tid & 7) * 8;
      float acc[8] = {0, 0, 0, 0, 0, 0, 0, 0};
      for (int k = 0; k < 128; ++k) {
        const float qa = Fg[k * 192 + 128 + a];
        const float4 h0 = *(const float4*)&sHu[k * 68 + u0];
        const float4 h1 = *(const float4*)&sHu[k * 68 + u0 + 4];
        acc[0] = fmaf(qa, h0.x, acc[0]); acc[1] = fmaf(qa, h0.y, acc[1]);
        acc[2] = fmaf(qa, h0.z, acc[2]); acc[3] = fmaf(qa, h0.w, acc[3]);
        acc[4] = fmaf(qa, h1.x, acc[4]); acc[5] = fmaf(qa, h1.y, acc[5]);
        acc[6] = fmaf(qa, h1.z, acc[6]); acc[7] = fmaf(qa, h1.w, acc[7]);
      }
      const int cb = (128 + a) * 192 + 128 + u0;
#pragma unroll
      for (int e = 0; e < 8; ++e) acc[e] += Cg[cb + e];
      *(float4*)&sQUU[a * 68 + u0]     = make_float4(acc[0], acc[1], acc[2], acc[3]);
      *(float4*)&sQUU[a * 68 + u0 + 4] = make_float4(acc[4], acc[5], acc[6], acc[7]);
    }
    {  // Qxu[j][u0..u0+15]
      const int j = tid >> 2, u0 = (tid & 3) * 16;
      float acc[16];
#pragma unroll
      for (int e = 0; e < 16; ++e) acc[e] = 0.f;
      for (int k = 0; k < 128; ++k) {
        const float fa = Fg[k * 192 + j];
        const float4 h0 = *(const float4*)&sHu[k * 68 + u0];
        const float4 h1 = *(const float4*)&sHu[k * 68 + u0 + 4];
        const float4 h2 = *(const float4*)&sHu[k * 68 + u0 + 8];
        const float4 h3 = *(const float4*)&sHu[k * 68 + u0 + 12];
        acc[0] = fmaf(fa, h0.x, acc[0]);  acc[1] = fmaf(fa, h0.y, acc[1]);
        acc[2] = fmaf(fa, h0.z, acc[2]);  acc[3] = fmaf(fa, h0.w, acc[3]);
        acc[4] = fmaf(fa, h1.x, acc[4]);  acc[5] = fmaf(fa, h1.y, acc[5]);
        acc[6] = fmaf(fa, h1.z, acc[6]);  acc[7] = fmaf(fa, h1.w, acc[7]);
        acc[8] = fmaf(fa, h2.x, acc[8]);  acc[9] = fmaf(fa, h2.y, acc[9]);
        acc[10] = fmaf(fa, h2.z, acc[10]); acc[11] = fmaf(fa, h2.w, acc[11]);
        acc[12] = fmaf(fa, h3.x, acc[12]); acc[13] = fmaf(fa, h3.y, acc[13]);
        acc[14] = fmaf(fa, h3.z, acc[14]); acc[15] = fmaf(fa, h3.w, acc[15]);
      }
      const int cb = j * 192 + 128 + u0;
#pragma unroll
      for (int e = 0; e < 16; ++e) acc[e] += Cg[cb + e];
      *(float4*)&sQXU[j * 68 + u0]      = make_float4(acc[0], acc[1], acc[2], acc[3]);
      *(float4*)&sQXU[j * 68 + u0 + 4]  = make_float4(acc[4], acc[5], acc[6], acc[7]);
      *(float4*)&sQXU[j * 68 + u0 + 8]  = make_float4(acc[8], acc[9], acc[10], acc[11]);
      *(float4*)&sQXU[j * 68 + u0 + 12] = make_float4(acc[12], acc[13], acc[14], acc[15]);
    }
    __syncthreads();

    // ===== Newton (fixed budget, warm, replicated & deterministic) =====
    {
      const int bg = tid & 7, aN = tid >> 3, b0 = bg * 8;
      if (it == 0) {
        float rsum = 0.f;
        if (tid < 64)
          for (int u = 0; u < 64; ++u) rsum += fabsf(sQUU[tid * 68 + u]);
        const float s = blk_reduce_max(rsum, sred, tid);
        const float invs = 1.f / s;
        for (int idx = tid; idx < 64 * 68; idx += TPB) {
          const int a2 = idx / 68, b2 = idx - a2 * 68;
          sX[idx] = (a2 == b2) ? invs : 0.f;
        }
        __syncthreads();
      }
      int budget = (it == 0) ? 12 : 2;
      for (int attempt = 0; attempt < 3; ++attempt) {
        for (int ns = 0; ns < budget; ++ns) {
          float t1[8] = {0, 0, 0, 0, 0, 0, 0, 0};
          for (int u = 0; u < 64; ++u) {
            const float qa = sQUU[aN * 68 + u];
            const float4 x0 = *(const float4*)&sX[u * 68 + b0];
            const float4 x1 = *(const float4*)&sX[u * 68 + b0 + 4];
            t1[0] = fmaf(qa, x0.x, t1[0]); t1[1] = fmaf(qa, x0.y, t1[1]);
            t1[2] = fmaf(qa, x0.z, t1[2]); t1[3] = fmaf(qa, x0.w, t1[3]);
            t1[4] = fmaf(qa, x1.x, t1[4]); t1[5] = fmaf(qa, x1.y, t1[5]);
            t1[6] = fmaf(qa, x1.z, t1[6]); t1[7] = fmaf(qa, x1.w, t1[7]);
          }
          *(float4*)&sT1[aN * 68 + b0]     = make_float4(t1[0], t1[1], t1[2], t1[3]);
          *(float4*)&sT1[aN * 68 + b0 + 4] = make_float4(t1[4], t1[5], t1[6], t1[7]);
          __syncthreads();
          float xn[8] = {0, 0, 0, 0, 0, 0, 0, 0};
          for (int u = 0; u < 64; ++u) {
            const float xa = sX[aN * 68 + u];
            const float4 t0 = *(const float4*)&sT1[u * 68 + b0];
            const float4 t4 = *(const float4*)&sT1[u * 68 + b0 + 4];
            xn[0] = fmaf(xa, t0.x, xn[0]); xn[1] = fmaf(xa, t0.y, xn[1]);
            xn[2] = fmaf(xa, t0.z, xn[2]); xn[3] = fmaf(xa, t0.w, xn[3]);
            xn[4] = fmaf(xa, t4.x, xn[4]); xn[5] = fmaf(xa, t4.y, xn[5]);
            xn[6] = fmaf(xa, t4.z, xn[6]); xn[7] = fmaf(xa, t4.w, xn[7]);
          }
          const float4 xo0 = *(const float4*)&sX[aN * 68 + b0];
          const float4 xo4 = *(const float4*)&sX[aN * 68 + b0 + 4];
          __syncthreads();
          *(float4*)&sX[aN * 68 + b0] =
              make_float4(2.f * xo0.x - xn[0], 2.f * xo0.y - xn[1],
                          2.f * xo0.z - xn[2], 2.f * xo0.w - xn[3]);
          *(float4*)&sX[aN * 68 + b0 + 4] =
              make_float4(2.f * xo4.x - xn[4], 2.f * xo4.y - xn[5],
                          2.f * xo4.z - xn[6], 2.f * xo4.w - xn[7]);
          __syncthreads();
        }
        float t1[8] = {0, 0, 0, 0, 0, 0, 0, 0};
        for (int u = 0; u < 64; ++u) {
          const float qa = sQUU[aN * 68 + u];
          const float4 x0 = *(const float4*)&sX[u * 68 + b0];
          const float4 x1 = *(const float4*)&sX[u * 68 + b0 + 4];
          t1[0] = fmaf(qa, x0.x, t1[0]); t1[1] = fmaf(qa, x0.y, t1[1]);
          t1[2] = fmaf(qa, x0.z, t1[2]); t1[3] = fmaf(qa, x0.w, t1[3]);
          t1[4] = fmaf(qa, x1.x, t1[4]); t1[5] = fmaf(qa, x1.y, t1[5]);
          t1[6] = fmaf(qa, x1.z, t1[6]); t1[7] = fmaf(qa, x1.w, t1[7]);
        }
        float rs_ = 0.f;
#pragma unroll
        for (int e = 0; e < 8; ++e)
          rs_ += fabsf(t1[e] - ((aN == b0 + e) ? 1.f : 0.f));
        rs_ += __shfl_xor(rs_, 1); rs_ += __shfl_xor(rs_, 2); rs_ += __shfl_xor(rs_, 4);
        if (!(rs_ == rs_)) rs_ = 1e30f;
        const float rmax = blk_reduce_max(rs_, sred, tid);
        if (rmax < 0.3f) break;
        if (attempt == 0) { budget = 3; continue; }
        {
          float rsum = 0.f;
          if (tid < 64)
            for (int u = 0; u < 64; ++u) rsum += fabsf(sQUU[tid * 68 + u]);
          const float s = blk_reduce_max(rsum, sred, tid);
          const float invs = 1.f / s;
          for (int idx = tid; idx < 64 * 68; idx += TPB) {
            const int a2 = idx / 68, b2 = idx - a2 * 68;
            sX[idx] = (a2 == b2) ? invs : 0.f;
          }
          __syncthreads();
          budget = 12;
        }
      }
    }

    // ===== D: k (replicated), cstep/const bookkeeping (replicated) =====
    if (tid < 64) sk[tid] = -dot_f4(&sX[tid * 68], &sq[128], 16);
    __syncthreads();
    {
      float p1 = 0.f, p2 = 0.f;
      if (tid < 64) {
        const float ta = dot_f4(&sQUU[tid * 68], sk, 16);
        p1 = sk[tid] * ta; p2 = sk[tid] * sq[128 + tid];
      }
      const float kQk = blk_reduce_sum(p1, sred, tid);
      const float kqu = blk_reduce_sum(p2, sred, tid);
      if (tid == 0) {
        const float cstep_ = 0.5f * kQk + kqu + 0.5f * sS[2] + sS[3];
        const float dc = cstep_ - sS[1];
        const float dcp = sS[4];
        sS[4] = dc; sS[1] = cstep_; sS[0] += cstep_;
        if (w == 0) out[ocOff + rrow] = sS[0];
        float r = (fabsf(dcp) > 1e-20f) ? dc / dcp : 0.85f;
        if (!(r == r)) r = 0.85f;
        r = fminf(fmaxf(r, -0.85f), 0.85f);
        const float e = -dc * r / (1.f - r);
        sS[5] = r; sS[6] = e;
        float ok = (fabsf(e) * (float)T * 0.35f <= 12.f && fabsf(dc) <= 2e-2f)
                       ? 1.f : 0.f;
        if (!(cstep_ == cstep_)) ok = 0.f;
        sS[7] = ok;
      }
      if (w == 0 && tid < 64) out[okOff + (size_t)rrow * 64 + tid] = sk[tid];
    }
    {  // K cols [8w, 8w+8)
      const int a = tid >> 3, jj = tid & 7, jcol = 8 * w + jj;
      out[(size_t)rrow * 8192 + a * 128 + jcol] =
          -dot_f4(&sX[a * 68], &sQXU[jcol * 68], 16);
    }
    {  // M[i][a] (sT1 dead -> sM overlay)
      const int i = tid >> 6, a2 = tid & 63;
      sM[i * 68 + a2] = dot_f4(&sQXU[(8 * w + i) * 68], &sX[a2 * 68], 16);
    }
    __syncthreads();

    // ===== F: Vn (Qxx via symmetry, fused) + vn + conv partials =====
    float dmax = 0.f, vmax = 0.f, dvp = 0.f, mvp = 0.f, chk = 0.f;
    {
      const int r = tid & 7, j0 = (tid >> 3) * 2, ig = 8 * w + r;
      float q0 = Cg[j0 * 192 + ig], q1 = Cg[(j0 + 1) * 192 + ig];
      const float* h8 = &sH8T[r * 132];
      for (int k4 = 0; k4 < 32; ++k4) {
        const float4 h = *(const float4*)&h8[k4 * 4];
        const float hv[4] = {h.x, h.y, h.z, h.w};
#pragma unroll
        for (int e = 0; e < 4; ++e) {
          const int m = k4 * 4 + e;
          q0 = fmaf(Fg[m * 192 + j0], hv[e], q0);
          q1 = fmaf(Fg[m * 192 + j0 + 1], hv[e], q1);
        }
      }
      const float a0 = dot_f4(&sM[r * 68], &sQXU[j0 * 68], 16);
      const float a1 = dot_f4(&sM[r * 68], &sQXU[(j0 + 1) * 68], 16);
      const float vn0 = q0 - a0, vn1 = q1 - a1;
      dmax = fmaxf(fabsf(vn0 - sVown[r * 132 + j0]),
                   fabsf(vn1 - sVown[r * 132 + j0 + 1]));
      vmax = fmaxf(fabsf(vn0), fabsf(vn1));
      chk += vn0 + vn1;
      sVown[r * 132 + j0] = vn0; sVown[r * 132 + j0 + 1] = vn1;
      out[oVOff + (size_t)rrow * 16384 + ig * 128 + j0] = vn0;
      out[oVOff + (size_t)rrow * 16384 + ig * 128 + j0 + 1] = vn1;
    }
    if (tid < 8) {
      const int ig = 8 * w + tid;
      const float va = sq[ig] + dot_f4(&sQXU[ig * 68], sk, 16);
      dvp = fabsf(va - svown[tid]); mvp = fabsf(va);
      chk += va;
      svown[tid] = va;
      out[ovOff + (size_t)rrow * 128 + ig] = va;
    }
    if (!(chk == chk)) { dmax = 1e30f; dvp = 1e30f; }
    {
      const float dV_w = blk_reduce_max(dmax, sred, tid);
      const float mV_w = blk_reduce_max(vmax, sred, tid);
      const float dv_w = blk_reduce_max(dvp, sred, tid);
      const float mv_w = blk_reduce_max(mvp, sred, tid);
      if (tid == 0) {
        convA[w] = dV_w; convA[16 + w] = mV_w;
        convA[32 + w] = dv_w; convA[48 + w] = mv_w;
      }
    }
  }

  if (w == 0 && tid == 0) {
    ((int*)ws)[0] = Sdone;
    ws[1] = sS[1]; ws[2] = sS[0]; ws[3] = sS[5]; ws[4] = sS[6];
    ws[5] = converged ? 1.f : 0.f;
  }
}

// ================= Round-10 proven coop kernel (fallback #1, gated) =================
__global__ __launch_bounds__(TPB) void lqr_coop(
    const float* __restrict__ Fg, const float* __restrict__ fg,
    const float* __restrict__ Cg, const float* __restrict__ cgv,
    float* __restrict__ out, float* __restrict__ ws, int T, int force)
{
  if (!force && ws[5] == 1.0f) return;
  cg::grid_group grid = cg::this_grid();
  const int tid = threadIdx.x;
  const int w = blockIdx.x;
  const int lane = tid & 63, wv = tid >> 6;
  const int ITCAP = 28;

  __shared__ __align__(16) float pool[39328];
  float* const sV   = pool;
  float* const sQXU = pool + 16896;
  float* const sQUU = pool + 25600;
  float* const sX   = pool + 29952;
  float* const sT1  = pool + 34304;
  float* const sZt  = sT1;
  float* const sM   = sT1;
  float* const svv  = pool + 38656;
  float* const sz   = svv + 128;
  float* const sq   = sz + 128;
  float* const sk   = sq + 192;
  float* const sf   = sk + 64;
  float* const sred = sf + 128;
  float* const sS   = sred + 16;
  float* const spz  = sS + 8;

  float* const Vg   = ws + 16;
  float* const vg   = Vg + 16384;
  float* const Qg   = vg + 128;
  float* const conv = Qg + 36864;
  float* const sentB = conv + 72;
  float* const sentE = conv + 88;

  const size_t okOff = (size_t)T * 8192;
  const size_t oVOff = okOff + (size_t)T * 64;
  const size_t ovOff = oVOff + (size_t)T * 16384;
  const size_t ocOff = ovOff + (size_t)T * 128;

  if (tid < 128) sf[tid] = fg[tid];
  if (tid == 0) {
    sS[0] = 0.f; sS[1] = 0.f; sS[4] = 0.f; sS[5] = 0.85f; sS[6] = 1e30f;
    sS[7] = 0.f; spz[0] = 0.f; spz[1] = 0.f;
  }
  for (int idx = w * TPB + tid; idx < 16384; idx += TPB * NWG) {
    const int i = idx >> 7, j = idx & 127;
    Vg[idx] = Cg[i * 192 + j];
  }
  if (w == 0 && tid < 128) vg[tid] = cgv[tid];
  if (tid == 0) sentE[w] = 100.5f + (float)w;
  __syncthreads();
  __threadfence();
  grid.sync();
  if (tid < NWG) {
    if (gload(&sentE[tid]) != 100.5f + (float)tid) spz[0] = 1.f;
  }
  __syncthreads();

  int Sdone = T;
  bool converged = false;

  if (spz[0] == 0.f) {
    for (int it = 0; it < ITCAP; ++it) {
      const int rrow = T - 1 - it;
#pragma unroll
      for (int qd = 0; qd < 8; ++qd) {
        const int idx = qd * TPB + tid;
        const int i = idx >> 5, j4 = idx & 31;
        const float4 v4 = gload4(&Vg[i * 128 + j4 * 4]);
        *(float4*)&sV[i * 132 + j4 * 4] = v4;
      }
      if (tid < 128) svv[tid] = gload(&vg[tid]);
      __syncthreads();

      if (tid < 128) sz[tid] = dot_f4(&sV[tid * 132], sf, 32) + svv[tid];
      __syncthreads();
      if (w == 0) {
        float p1 = 0.f, p2 = 0.f;
        if (tid < 128) {
          const float vfk = sz[tid] - svv[tid];
          p1 = sf[tid] * vfk; p2 = sf[tid] * svv[tid];
        }
        const float fVf = blk_reduce_sum(p1, sred, tid);
        const float fv  = blk_reduce_sum(p2, sred, tid);
        if (tid == 0) { sS[2] = fVf; sS[3] = fv; }
      }
      if (tid < 192) {
        float qa = cgv[tid];
#pragma unroll 4
        for (int k = 0; k < 128; ++k) qa = fmaf(Fg[k * 192 + tid], sz[k], qa);
        sq[tid] = qa;
      }
      {
        const int kk = lane >> 2, jj = lane & 3;
        const int k = wv * 16 + kk;
        const int j0 = w * 12;
        const float* vrow = &sV[k * 132];
        float a0 = 0.f, a1 = 0.f, a2 = 0.f;
#pragma unroll 2
        for (int m4 = 0; m4 < 32; ++m4) {
          const float4 v4 = *(const float4*)&vrow[m4 * 4];
          const int m = m4 * 4;
          a0 = fmaf(v4.x, Fg[(m + 0) * 192 + j0 + jj], a0);
          a0 = fmaf(v4.y, Fg[(m + 1) * 192 + j0 + jj], a0);
          a0 = fmaf(v4.z, Fg[(m + 2) * 192 + j0 + jj], a0);
          a0 = fmaf(v4.w, Fg[(m + 3) * 192 + j0 + jj], a0);
          a1 = fmaf(v4.x, Fg[(m + 0) * 192 + j0 + jj + 4], a1);
          a1 = fmaf(v4.y, Fg[(m + 1) * 192 + j0 + jj + 4], a1);
          a1 = fmaf(v4.z, Fg[(m + 2) * 192 + j0 + jj + 4], a1);
          a1 = fmaf(v4.w, Fg[(m + 3) * 192 + j0 + jj + 4], a1);
          a2 = fmaf(v4.x, Fg[(m + 0) * 192 + j0 + jj + 8], a2);
          a2 = fmaf(v4.y, Fg[(m + 1) * 192 + j0 + jj + 8], a2);
          a2 = fmaf(v4.z, Fg[(m + 2) * 192 + j0 + jj + 8], a2);
          a2 = fmaf(v4.w, Fg[(m + 3) * 192 + j0 + jj + 8], a2);
        }
        sZt[jj * 132 + k] = a0;
        sZt[(jj + 4) * 132 + k] = a1;
        sZt[(jj + 8) * 132 + k] = a2;
      }
      __syncthreads();
      for (int b = wv; b < 36; b += 8) {
        const int i = (b % 12) * 16 + (lane & 15);
        const int jl = (b / 12) * 4 + (lane >> 4);
        const int jq = w * 12 + jl;
        const float* zrow = &sZt[jl * 132];
        float acc = 0.f;
#pragma unroll 2
        for (int k4 = 0; k4 < 32; ++k4) {
          const float4 z4 = *(const float4*)&zrow[k4 * 4];
          const int k = k4 * 4;
          acc = fmaf(Fg[(k + 0) * 192 + i], z4.x, acc);
          acc = fmaf(Fg[(k + 1) * 192 + i], z4.y, acc);
          acc = fmaf(Fg[(k + 2) * 192 + i], z4.z, acc);
          acc = fmaf(Fg[(k + 3) * 192 + i], z4.w, acc);
        }
        Qg[jq * 192 + i] = Cg[jq * 192 + i] + acc;
      }
      if (tid == 0) sentB[w] = (float)(it * 128 + w + 1);
      __syncthreads();
      __threadfence();
      grid.sync();
      if (tid < NWG) {
        if (gload(&sentB[tid]) != (float)(it * 128 + tid + 1)) spz[0] = 1.f;
      }
      __syncthreads();
      if (spz[0] != 0.f) break;

#pragma unroll
      for (int qd = 0; qd < 4; ++qd) {
        const int idx = qd * TPB + tid;
        const int j = idx >> 4, u4 = idx & 15;
        const float4 v4 = gload4(&Qg[j * 192 + 128 + u4 * 4]);
        *(float4*)&sQXU[j * 68 + u4 * 4] = v4;
      }
#pragma unroll
      for (int qd = 0; qd < 2; ++qd) {
        const int idx = qd * TPB + tid;
        const int a = idx >> 4, u4 = idx & 15;
        const float4 v4 = gload4(&Qg[(128 + a) * 192 + 128 + u4 * 4]);
        *(float4*)&sQUU[a * 68 + u4 * 4] = v4;
      }
      __syncthreads();

      {
        const int bg = tid & 7, aN = tid >> 3, b0 = bg * 8;
        if (it == 0) {
          float rsum = 0.f;
          if (tid < 64)
            for (int u = 0; u < 64; ++u) rsum += fabsf(sQUU[tid * 68 + u]);
          const float s = blk_reduce_max(rsum, sred, tid);
          const float invs = 1.f / s;
          for (int idx = tid; idx < 64 * 68; idx += TPB) {
            const int a2 = idx / 68, b2 = idx - a2 * 68;
            sX[idx] = (a2 == b2) ? invs : 0.f;
          }
          __syncthreads();
        }
        int budget = (it == 0) ? 12 : 2;
        for (int attempt = 0; attempt < 3; ++attempt) {
          for (int ns = 0; ns < budget; ++ns) {
            float t1[8] = {0, 0, 0, 0, 0, 0, 0, 0};
            for (int u = 0; u < 64; ++u) {
              const float qa = sQUU[aN * 68 + u];
              const float4 x0 = *(const float4*)&sX[u * 68 + b0];
              const float4 x1 = *(const float4*)&sX[u * 68 + b0 + 4];
              t1[0] = fmaf(qa, x0.x, t1[0]); t1[1] = fmaf(qa, x0.y, t1[1]);
              t1[2] = fmaf(qa, x0.z, t1[2]); t1[3] = fmaf(qa, x0.w, t1[3]);
              t1[4] = fmaf(qa, x1.x, t1[4]); t1[5] = fmaf(qa, x1.y, t1[5]);
              t1[6] = fmaf(qa, x1.z, t1[6]); t1[7] = fmaf(qa, x1.w, t1[7]);
            }
            *(float4*)&sT1[aN * 68 + b0]     = make_float4(t1[0], t1[1], t1[2], t1[3]);
            *(float4*)&sT1[aN * 68 + b0 + 4] = make_float4(t1[4], t1[5], t1[6], t1[7]);
            __syncthreads();
            float xn[8] = {0, 0, 0, 0, 0, 0, 0, 0};
            for (int u = 0; u < 64; ++u) {
              const float xa = sX[aN * 68 + u];
              const float4 t0 = *(const float4*)&sT1[u * 68 + b0];
              const float4 t4 = *(const float4*)&sT1[u * 68 + b0 + 4];
              xn[0] = fmaf(xa, t0.x, xn[0]); xn[1] = fmaf(xa, t0.y, xn[1]);
              xn[2] = fmaf(xa, t0.z, xn[2]); xn[3] = fmaf(xa, t0.w, xn[3]);
              xn[4] = fmaf(xa, t4.x, xn[4]); xn[5] = fmaf(xa, t4.y, xn[5]);
              xn[6] = fmaf(xa, t4.z, xn[6]); xn[7] = fmaf(xa, t4.w, xn[7]);
            }
            const float4 xo0 = *(const float4*)&sX[aN * 68 + b0];
            const float4 xo4 = *(const float4*)&sX[aN * 68 + b0 + 4];
            __syncthreads();
            *(float4*)&sX[aN * 68 + b0] =
                make_float4(2.f * xo0.x - xn[0], 2.f * xo0.y - xn[1],
                            2.f * xo0.z - xn[2], 2.f * xo0.w - xn[3]);
            *(float4*)&sX[aN * 68 + b0 + 4] =
                make_float4(2.f * xo4.x - xn[4], 2.f * xo4.y - xn[5],
                            2.f * xo4.z - xn[6], 2.f * xo4.w - xn[7]);
            __syncthreads();
          }
          float t1[8] = {0, 0, 0, 0, 0, 0, 0, 0};
          for (int u = 0; u < 64; ++u) {
            const float qa = sQUU[aN * 68 + u];
            const float4 x0 = *(const float4*)&sX[u * 68 + b0];
            const float4 x1 = *(const float4*)&sX[u * 68 + b0 + 4];
            t1[0] = fmaf(qa, x0.x, t1[0]); t1[1] = fmaf(qa, x0.y, t1[1]);
            t1[2] = fmaf(qa, x0.z, t1[2]); t1[3] = fmaf(qa, x0.w, t1[3]);
            t1[4] = fmaf(qa, x1.x, t1[4]); t1[5] = fmaf(qa, x1.y, t1[5]);
            t1[6] = fmaf(qa, x1.z, t1[6]); t1[7] = fmaf(qa, x1.w, t1[7]);
          }
          float rs_ = 0.f;
#pragma unroll
          for (int e = 0; e < 8; ++e)
            rs_ += fabsf(t1[e] - ((aN == b0 + e) ? 1.f : 0.f));
          rs_ += __shfl_xor(rs_, 1); rs_ += __shfl_xor(rs_, 2); rs_ += __shfl_xor(rs_, 4);
          if (!(rs_ == rs_)) rs_ = 1e30f;
          const float rmax = blk_reduce_max(rs_, sred, tid);
          if (rmax < 0.3f) break;
          if (attempt == 0) { budget = 3; continue; }
          {
            float rsum = 0.f;
            if (tid < 64)
              for (int u = 0; u < 64; ++u) rsum += fabsf(sQUU[tid * 68 + u]);
            const float s = blk_reduce_max(rsum, sred, tid);
            const float invs = 1.f / s;
            for (int idx = tid; idx < 64 * 68; idx += TPB) {
              const int a2 = idx / 68, b2 = idx - a2 * 68;
              sX[idx] = (a2 == b2) ? invs : 0.f;
            }
            __syncthreads();
            budget = 12;
          }
        }
      }

      if (tid < 64) sk[tid] = -dot_f4(&sX[tid * 68], &sq[128], 16);
      __syncthreads();
      if (w == 0) {
        if (tid < 64) out[okOff + (size_t)rrow * 64 + tid] = sk[tid];
        float p1 = 0.f, p2 = 0.f;
        if (tid < 64) {
          const float ta = dot_f4(&sQUU[tid * 68], sk, 16);
          p1 = sk[tid] * ta; p2 = sk[tid] * sq[128 + tid];
        }
        const float kQk = blk_reduce_sum(p1, sred, tid);
        const float kqu = blk_reduce_sum(p2, sred, tid);
        if (tid == 0) {
          const float cstep_ = 0.5f * kQk + kqu + 0.5f * sS[2] + sS[3];
          const float dc = cstep_ - sS[1];
          const float dcp = sS[4];
          sS[4] = dc; sS[1] = cstep_; sS[0] += cstep_;
          out[ocOff + rrow] = sS[0];
          float r = (fabsf(dcp) > 1e-20f) ? dc / dcp : 0.85f;
          if (!(r == r)) r = 0.85f;
          r = fminf(fmaxf(r, -0.85f), 0.85f);
          const float e = -dc * r / (1.f - r);
          sS[5] = r; sS[6] = e;
          float ok = (fabsf(e) * (float)T * 0.35f <= 12.f && fabsf(dc) <= 2e-2f)
                         ? 1.f : 0.f;
          if (!(cstep_ == cstep_)) ok = 0.f;
          sS[7] = ok;
        }
      }
      {
        const int a = tid >> 3, jj = tid & 7, jcol = w * 8 + jj;
        const float kv = -dot_f4(&sX[a * 68], &sQXU[jcol * 68], 16);
        out[(size_t)rrow * 8192 + a * 128 + jcol] = kv;
      }
      {
        const int i = tid >> 6, a = tid & 63;
        sM[i * 68 + a] = dot_f4(&sQXU[(w * 8 + i) * 68], &sX[a * 68], 16);
      }
      __syncthreads();
      float dmax = 0.f, vmax = 0.f, dvp = 0.f, mvp = 0.f, chk = 0.f;
      if (tid < 256) {
        const int i = tid >> 5, j4 = tid & 31, ig = w * 8 + i;
        const float4 qxx = gload4(&Qg[ig * 192 + j4 * 4]);
        const float4 vold = *(const float4*)&sV[ig * 132 + j4 * 4];
        const float qv[4] = {qxx.x, qxx.y, qxx.z, qxx.w};
        const float vo[4] = {vold.x, vold.y, vold.z, vold.w};
        float vn[4];
#pragma unroll
        for (int e = 0; e < 4; ++e) {
          const float acc = dot_f4(&sM[i * 68], &sQXU[(j4 * 4 + e) * 68], 16);
          vn[e] = qv[e] - acc;
          dmax = fmaxf(dmax, fabsf(vn[e] - vo[e]));
          vmax = fmaxf(vmax, fabsf(vn[e]));
          chk += vn[e];
        }
        const float4 vq = make_float4(vn[0], vn[1], vn[2], vn[3]);
        *(float4*)&Vg[ig * 128 + j4 * 4] = vq;
        *(float4*)&out[oVOff + (size_t)rrow * 16384 + ig * 128 + j4 * 4] = vq;
      }
      if (tid < 8) {
        const int ig = w * 8 + tid;
        const float va = sq[ig] + dot_f4(&sQXU[ig * 68], sk, 16);
        dvp = fabsf(va - svv[ig]); mvp = fabsf(va);
        chk += va;
        vg[ig] = va;
        out[ovOff + (size_t)rrow * 128 + ig] = va;
      }
      if (!(chk == chk)) { dmax = 1e30f; dvp = 1e30f; }
      const float dV_w = blk_reduce_max(dmax, sred, tid);
      const float mV_w = blk_reduce_max(vmax, sred, tid);
      const float dv_w = blk_reduce_max(dvp, sred, tid);
      const float mv_w = blk_reduce_max(mvp, sred, tid);
      if (tid == 0) {
        conv[w] = dV_w; conv[16 + w] = mV_w;
        conv[32 + w] = dv_w; conv[48 + w] = mv_w;
        if (w == 0) conv[64] = sS[7];
        sentE[w] = (float)(it * 128 + 64 + w + 1);
      }
      __syncthreads();
      __threadfence();
      grid.sync();
      if (tid < NWG) {
        if (gload(&sentE[tid]) != (float)(it * 128 + 64 + tid + 1)) spz[0] = 1.f;
      }
      if (tid < 16) {
        float c0 = gload(&conv[tid]), c1 = gload(&conv[16 + tid]),
              c2 = gload(&conv[32 + tid]), c3 = gload(&conv[48 + tid]);
#pragma unroll
        for (int o = 8; o > 0; o >>= 1) {
          c0 = fmaxf(c0, __shfl_down(c0, o));
          c1 = fmaxf(c1, __shfl_down(c1, o));
          c2 = fmaxf(c2, __shfl_down(c2, o));
          c3 = fmaxf(c3, __shfl_down(c3, o));
        }
        if (tid == 0) {
          const float cok = gload(&conv[64]);
          spz[1] = (it >= 3 && c0 <= 2e-3f * c1 &&
                    c2 <= 4e-3f * fmaxf(1.f, c3) && cok != 0.f) ? 1.f : 0.f;
        }
      }
      __syncthreads();
      if (spz[0] != 0.f) break;
      if (spz[1] != 0.f) { Sdone = it + 1; converged = true; break; }
    }
  }

  if (w == 0 && tid == 0) {
    ((int*)ws)[0] = Sdone;
    ws[1] = sS[1]; ws[2] = sS[0]; ws[3] = sS[5]; ws[4] = sS[6];
    ws[5] = converged ? 1.f : 0.f;
  }
}

// ================= Fallback #2: proven single-WG kernel =================
__global__ __launch_bounds__(TPB) void lqr_fb(
    const float* __restrict__ Fg, const float* __restrict__ fg,
    const float* __restrict__ Cg, const float* __restrict__ cg,
    float* __restrict__ out, float* __restrict__ ws, int T, int force)
{
  if (!force && ws[5] == 1.0f) return;
  const int tid = threadIdx.x;

  __shared__ __align__(16) float pool[39584];
  float* const sV   = pool;
  float* const sQXU = pool + 16896;
  float* const sQUU = pool + 25600;
  float* const sTMP = pool + 29952;
  float* const sX   = pool + 34560;
  float* const sWT  = sQUU;
  float* const sf   = pool + 38912;
  float* const sv   = sf + 128;
  float* const sz   = sv + 128;
  float* const sq   = sz + 128;
  float* const sk   = sq + 192;
  float* const sred = sk + 64;
  float* const sS   = sred + 16;

  const size_t okOff = (size_t)T * 8192;
  const size_t oVOff = okOff + (size_t)T * 64;
  const size_t ovOff = oVOff + (size_t)T * 16384;
  const size_t ocOff = ovOff + (size_t)T * 128;

  for (int idx = tid; idx < 128 * 128; idx += TPB) {
    const int i = idx >> 7, j = idx & 127;
    sV[i * 132 + j] = Cg[i * 192 + j];
  }
  if (tid < 128) { sf[tid] = fg[tid]; sv[tid] = cg[tid]; }
  if (tid == 0) {
    sS[0] = 0.f; sS[1] = 0.f; sS[3] = 0.f;
    sS[5] = 0.85f; sS[6] = 1e30f; sS[7] = 0.f;
  }
  __syncthreads();

  int Sdone = T;

  for (int it = 0; it < T; ++it) {
    const int rrow = T - 1 - it;
    float* const outVrow = out + oVOff + (size_t)rrow * 16384;

    float wv = 0.f;
    if (tid < 128) wv = dot_f4(&sV[tid * 132], sf, 32);
    float p1 = 0.f, p2 = 0.f;
    if (tid < 128) { p1 = sf[tid] * wv; p2 = sf[tid] * sv[tid]; sz[tid] = wv + sv[tid]; }
    const float fVf = blk_reduce_sum(p1, sred, tid);
    const float fv  = blk_reduce_sum(p2, sred, tid);
    if (tid < 192) {
      float qa = cg[tid];
#pragma unroll 4
      for (int k = 0; k < 128; ++k) qa = fmaf(Fg[k * 192 + tid], sz[k], qa);
      sq[tid] = qa;
    }
    __syncthreads();

    for (int p = 0; p < 6; ++p) {
      const int j0 = p * 32;
      {
        const int jp = tid & 15, kg = tid >> 4;
        float h0[4] = {0, 0, 0, 0}, h1[4] = {0, 0, 0, 0};
        for (int m4 = 0; m4 < 32; ++m4) {
          const float2 f0 = *(const float2*)&Fg[(m4 * 4 + 0) * 192 + j0 + 2 * jp];
          const float2 f1 = *(const float2*)&Fg[(m4 * 4 + 1) * 192 + j0 + 2 * jp];
          const float2 f2 = *(const float2*)&Fg[(m4 * 4 + 2) * 192 + j0 + 2 * jp];
          const float2 f3 = *(const float2*)&Fg[(m4 * 4 + 3) * 192 + j0 + 2 * jp];
#pragma unroll
          for (int r = 0; r < 4; ++r) {
            const float4 a = *(const float4*)&sV[(kg * 4 + r) * 132 + m4 * 4];
            h0[r] = fmaf(a.x, f0.x,
                    fmaf(a.y, f1.x, fmaf(a.z, f2.x, fmaf(a.w, f3.x, h0[r]))));
            h1[r] = fmaf(a.x, f0.y,
                    fmaf(a.y, f1.y, fmaf(a.z, f2.y, fmaf(a.w, f3.y, h1[r]))));
          }
        }
        *(float4*)&sTMP[(2 * jp + 0) * 132 + kg * 4] =
            make_float4(h0[0], h0[1], h0[2], h0[3]);
        *(float4*)&sTMP[(2 * jp + 1) * 132 + kg * 4] =
            make_float4(h1[0], h1[1], h1[2], h1[3]);
        __syncthreads();
      }
      if (p < 4) {
        const int jj = tid & 31, ig = tid >> 5, i0 = ig * 12, j = j0 + jj;
        float qa[12] = {0, 0, 0, 0, 0, 0, 0, 0, 0, 0, 0, 0};
        for (int k4 = 0; k4 < 32; ++k4) {
          const float4 hb = *(const float4*)&sTMP[jj * 132 + k4 * 4];
          const float hbv[4] = {hb.x, hb.y, hb.z, hb.w};
#pragma unroll
          for (int e = 0; e < 4; ++e) {
            const int k = k4 * 4 + e;
            const float hbe = hbv[e];
            const float4 a0 = *(const float4*)&Fg[k * 192 + i0];
            const float4 a1 = *(const float4*)&Fg[k * 192 + i0 + 4];
            const float4 a2 = *(const float4*)&Fg[k * 192 + i0 + 8];
            qa[0] = fmaf(a0.x, hbe, qa[0]); qa[1] = fmaf(a0.y, hbe, qa[1]);
            qa[2] = fmaf(a0.z, hbe, qa[2]); qa[3] = fmaf(a0.w, hbe, qa[3]);
            qa[4] = fmaf(a1.x, hbe, qa[4]); qa[5] = fmaf(a1.y, hbe, qa[5]);
            qa[6] = fmaf(a1.z, hbe, qa[6]); qa[7] = fmaf(a1.w, hbe, qa[7]);
            qa[8] = fmaf(a2.x, hbe, qa[8]); qa[9] = fmaf(a2.y, hbe, qa[9]);
            qa[10] = fmaf(a2.z, hbe, qa[10]); qa[11] = fmaf(a2.w, hbe, qa[11]);
          }
        }
#pragma unroll
        for (int r = 0; r < 12; ++r) {
          const int i = i0 + r;
          const float val = Cg[i * 192 + j] + qa[r];
          if (i < 128) outVrow[i * 128 + j] = val;
          else         sQXU[j * 68 + (i - 128)] = val;
        }
        __syncthreads();
      } else {
        const int jj = tid & 31, ug = tid >> 5, u0 = ug * 4;
        float qa[4] = {0, 0, 0, 0};
        for (int k4 = 0; k4 < 32; ++k4) {
          const float4 hb = *(const float4*)&sTMP[jj * 132 + k4 * 4];
          const float hbv[4] = {hb.x, hb.y, hb.z, hb.w};
#pragma unroll
          for (int e = 0; e < 4; ++e) {
            const int k = k4 * 4 + e;
            const float hbe = hbv[e];
            const float4 a0 = *(const float4*)&Fg[k * 192 + 128 + u0];
            qa[0] = fmaf(a0.x, hbe, qa[0]); qa[1] = fmaf(a0.y, hbe, qa[1]);
            qa[2] = fmaf(a0.z, hbe, qa[2]); qa[3] = fmaf(a0.w, hbe, qa[3]);
          }
        }
#pragma unroll
        for (int r = 0; r < 4; ++r)
          sQUU[(u0 + r) * 68 + (j0 - 128 + jj)] =
              Cg[(128 + u0 + r) * 192 + j0 + jj] + qa[r];
        __syncthreads();
      }
    }

    {
      const int bg = tid & 7, aN = tid >> 3, b0 = bg * 8;
      if (it == 0) {
        float rsum = 0.f;
        if (tid < 64)
          for (int u = 0; u < 64; ++u) rsum += fabsf(sQUU[tid * 68 + u]);
        const float s = blk_reduce_max(rsum, sred, tid);
        const float invs = 1.f / s;
        for (int idx = tid; idx < 64 * 68; idx += TPB) {
          const int a2 = idx / 68, b2 = idx - a2 * 68;
          sX[idx] = (a2 == b2) ? invs : 0.f;
        }
        __syncthreads();
      }
      int budget = (it == 0) ? 12 : 2;
      for (int attempt = 0; attempt < 3; ++attempt) {
        for (int ns = 0; ns < budget; ++ns) {
          float t1[8] = {0, 0, 0, 0, 0, 0, 0, 0};
          for (int u = 0; u < 64; ++u) {
            const float qa = sQUU[aN * 68 + u];
            const float4 x0 = *(const float4*)&sX[u * 68 + b0];
            const float4 x1 = *(const float4*)&sX[u * 68 + b0 + 4];
            t1[0] = fmaf(qa, x0.x, t1[0]); t1[1] = fmaf(qa, x0.y, t1[1]);
            t1[2] = fmaf(qa, x0.z, t1[2]); t1[3] = fmaf(qa, x0.w, t1[3]);
            t1[4] = fmaf(qa, x1.x, t1[4]); t1[5] = fmaf(qa, x1.y, t1[5]);
            t1[6] = fmaf(qa, x1.z, t1[6]); t1[7] = fmaf(qa, x1.w, t1[7]);
          }
          *(float4*)&sTMP[aN * 68 + b0]     = make_float4(t1[0], t1[1], t1[2], t1[3]);
          *(float4*)&sTMP[aN * 68 + b0 + 4] = make_float4(t1[4], t1[5], t1[6], t1[7]);
          __syncthreads();
          float xn[8] = {0, 0, 0, 0, 0, 0, 0, 0};
          for (int u = 0; u < 64; ++u) {
            const float xa = sX[aN * 68 + u];
            const float4 t0 = *(const float4*)&sTMP[u * 68 + b0];
            const float4 t4 = *(const float4*)&sTMP[u * 68 + b0 + 4];
            xn[0] = fmaf(xa, t0.x, xn[0]); xn[1] = fmaf(xa, t0.y, xn[1]);
            xn[2] = fmaf(xa, t0.z, xn[2]); xn[3] = fmaf(xa, t0.w, xn[3]);
            xn[4] = fmaf(xa, t4.x, xn[4]); xn[5] = fmaf(xa, t4.y, xn[5]);
            xn[6] = fmaf(xa, t4.z, xn[6]); xn[7] = fmaf(xa, t4.w, xn[7]);
          }
          const float4 xo0 = *(const float4*)&sX[aN * 68 + b0];
          const float4 xo4 = *(const float4*)&sX[aN * 68 + b0 + 4];
          __syncthreads();
          *(float4*)&sX[aN * 68 + b0] =
              make_float4(2.f * xo0.x - xn[0], 2.f * xo0.y - xn[1],
                          2.f * xo0.z - xn[2], 2.f * xo0.w - xn[3]);
          *(float4*)&sX[aN * 68 + b0 + 4] =
              make_float4(2.f * xo4.x - xn[4], 2.f * xo4.y - xn[5],
                          2.f * xo4.z - xn[6], 2.f * xo4.w - xn[7]);
          __syncthreads();
        }
        float t1[8] = {0, 0, 0, 0, 0, 0, 0, 0};
        for (int u = 0; u < 64; ++u) {
          const float qa = sQUU[aN * 68 + u];
          const float4 x0 = *(const float4*)&sX[u * 68 + b0];
          const float4 x1 = *(const float4*)&sX[u * 68 + b0 + 4];
          t1[0] = fmaf(qa, x0.x, t1[0]); t1[1] = fmaf(qa, x0.y, t1[1]);
          t1[2] = fmaf(qa, x0.z, t1[2]); t1[3] = fmaf(qa, x0.w, t1[3]);
          t1[4] = fmaf(qa, x1.x, t1[4]); t1[5] = fmaf(qa, x1.y, t1[5]);
          t1[6] = fmaf(qa, x1.z, t1[6]); t1[7] = fmaf(qa, x1.w, t1[7]);
        }
        float rs_ = 0.f;
#pragma unroll
        for (int e = 0; e < 8; ++e)
          rs_ += fabsf(t1[e] - ((aN == b0 + e) ? 1.f : 0.f));
        rs_ += __shfl_xor(rs_, 1); rs_ += __shfl_xor(rs_, 2); rs_ += __shfl_xor(rs_, 4);
        if (!(rs_ == rs_)) rs_ = 1e30f;
        const float rmax = blk_reduce_max(rs_, sred, tid);
        if (rmax < 0.3f) break;
        if (attempt == 0) { budget = 3; continue; }
        {
          float rsum = 0.f;
          if (tid < 64)
            for (int u = 0; u < 64; ++u) rsum += fabsf(sQUU[tid * 68 + u]);
          const float s = blk_reduce_max(rsum, sred, tid);
          const float invs = 1.f / s;
          for (int idx = tid; idx < 64 * 68; idx += TPB) {
            const int a2 = idx / 68, b2 = idx - a2 * 68;
            sX[idx] = (a2 == b2) ? invs : 0.f;
          }
          __syncthreads();
          budget = 12;
        }
      }
    }

    float kQk_p = 0.f, kqu_p = 0.f;
    if (tid < 64) {
      const float ka = -dot_f4(&sX[tid * 68], &sq[128], 16);
      sk[tid] = ka;
      out[okOff + (size_t)rrow * 64 + tid] = ka;
    }
    __syncthreads();
    if (tid < 64) {
      const float ta = dot_f4(&sQUU[tid * 68], sk, 16);
      kQk_p = sk[tid] * ta;
      kqu_p = sk[tid] * sq[128 + tid];
    }
    const float kQk = blk_reduce_sum(kQk_p, sred, tid);
    const float kqu = blk_reduce_sum(kqu_p, sred, tid);
    if (tid == 0) {
      const float cstep_ = 0.5f * kQk + kqu + 0.5f * fVf + fv;
      const float dc  = cstep_ - sS[1];
      const float dcp = sS[3];
      sS[3] = dc; sS[1] = cstep_; sS[0] += cstep_;
      out[ocOff + rrow] = sS[0];
      float r = (fabsf(dcp) > 1e-20f) ? dc / dcp : 0.85f;
      if (!(r == r)) r = 0.85f;
      r = fminf(fmaxf(r, -0.85f), 0.85f);
      const float e = -dc * r / (1.f - r);
      sS[5] = r; sS[6] = e;
      sS[7] = (fabsf(e) * (float)T * 0.35f <= 12.f && fabsf(dc) <= 2e-2f) ? 1.f : 0.f;
    }
    __syncthreads();

    {
      const int ag = tid & 3, j = tid >> 2, a0 = ag * 16;
      float w[16] = {0, 0, 0, 0, 0, 0, 0, 0, 0, 0, 0, 0, 0, 0, 0, 0};
      for (int u = 0; u < 64; ++u) {
        const float qx_ = sQXU[j * 68 + u];
        const float4 x0 = *(const float4*)&sX[u * 68 + a0];
        const float4 x1 = *(const float4*)&sX[u * 68 + a0 + 4];
        const float4 x2 = *(const float4*)&sX[u * 68 + a0 + 8];
        const float4 x3 = *(const float4*)&sX[u * 68 + a0 + 12];
        const float xv[16] = {x0.x, x0.y, x0.z, x0.w, x1.x, x1.y, x1.z, x1.w,
                              x2.x, x2.y, x2.z, x2.w, x3.x, x3.y, x3.z, x3.w};
#pragma unroll
        for (int e = 0; e < 16; ++e) w[e] = fmaf(qx_, xv[e], w[e]);
      }
      *(float4*)&sWT[j * 68 + a0]      = make_float4(w[0], w[1], w[2], w[3]);
      *(float4*)&sWT[j * 68 + a0 + 4]  = make_float4(w[4], w[5], w[6], w[7]);
      *(float4*)&sWT[j * 68 + a0 + 8]  = make_float4(w[8], w[9], w[10], w[11]);
      *(float4*)&sWT[j * 68 + a0 + 12] = make_float4(w[12], w[13], w[14], w[15]);
      float* const outK = out + (size_t)rrow * 8192;
#pragma unroll
      for (int e = 0; e < 16; ++e) outK[(a0 + e) * 128 + j] = -w[e];
      __syncthreads();
    }

    {
      const int jg = tid & 3, i = tid >> 2;
      float acc[32];
#pragma unroll
      for (int r = 0; r < 32; ++r) acc[r] = 0.f;
      for (int u4 = 0; u4 < 16; ++u4) {
        const float4 qa = *(const float4*)&sQXU[i * 68 + u4 * 4];
#pragma unroll
        for (int r = 0; r < 32; ++r) {
          const float4 wb = *(const float4*)&sWT[(jg + 4 * r) * 68 + u4 * 4];
          acc[r] += qa.x * wb.x + qa.y * wb.y + qa.z * wb.z + qa.w * wb.w;
        }
      }
      float dmax = 0.f, vmax = 0.f;
#pragma unroll
      for (int r = 0; r < 32; ++r) {
        const int j = jg + 4 * r;
        const float vn_ = outVrow[i * 128 + j] - acc[r];
        dmax = fmaxf(dmax, fabsf(vn_ - sV[i * 132 + j]));
        vmax = fmaxf(vmax, fabsf(vn_));
        sV[i * 132 + j] = vn_;
        outVrow[i * 128 + j] = vn_;
      }
      float dv_p = 0.f, mv_p = 0.f;
      if (tid < 128) {
        float va = sq[tid];
        for (int u = 0; u < 64; ++u) va = fmaf(sQXU[tid * 68 + u], sk[u], va);
        dv_p = fabsf(va - sv[tid]); mv_p = fabsf(va);
        sv[tid] = va;
        out[ovOff + (size_t)rrow * 128 + tid] = va;
      }
      const float dV = blk_reduce_max(dmax, sred, tid);
      const float mV = blk_reduce_max(vmax, sred, tid);
      const float dv = blk_reduce_max(dv_p, sred, tid);
      const float mv = blk_reduce_max(mv_p, sred, tid);
      if (it >= 3 && dV <= 2e-3f * mV && dv <= 4e-3f * fmaxf(1.f, mv) &&
          sS[7] != 0.f) {
        Sdone = it + 1; break;
      }
    }
  }

  if (tid == 0) {
    ((int*)ws)[0] = Sdone;
    ws[1] = sS[1]; ws[2] = sS[0]; ws[3] = sS[5]; ws[4] = sS[6];
  }
}

// ---------------- Kernel B: replicate converged rows + geometric const ----------------
__global__ __launch_bounds__(256) void lqr_fill(
    const float* __restrict__ ws, float* __restrict__ out, int T)
{
  const int S = ((const int*)ws)[0];
  const float cstep = ws[1];
  const float cbase = ws[2];
  const float rho   = ws[3];
  const float e     = ws[4];
  const int r = blockIdx.x;
  const int it = T - 1 - r;
  if (it < S) return;
  const int rs = T - S;
  const int tid = threadIdx.x;
  const size_t okOff = (size_t)T * 8192;
  const size_t oVOff = okOff + (size_t)T * 64;
  const size_t ovOff = oVOff + (size_t)T * 16384;
  const size_t ocOff = ovOff + (size_t)T * 128;

  const float4* __restrict__ sK = (const float4*)(out + (size_t)rs * 8192);
  float4* __restrict__ dK = (float4*)(out + (size_t)r * 8192);
  for (int i = tid; i < 2048; i += 256) dK[i] = sK[i];
  const float4* __restrict__ sVr = (const float4*)(out + oVOff + (size_t)rs * 16384);
  float4* __restrict__ dV = (float4*)(out + oVOff + (size_t)r * 16384);
  for (int i = tid; i < 4096; i += 256) dV[i] = sVr[i];
  if (tid < 16)
    ((float4*)(out + okOff + (size_t)r * 64))[tid] =
        ((const float4*)(out + okOff + (size_t)rs * 64))[tid];
  if (tid >= 32 && tid < 64) {
    const int q = tid - 32;
    ((float4*)(out + ovOff + (size_t)r * 128))[q] =
        ((const float4*)(out + ovOff + (size_t)rs * 128))[q];
  }
  if (tid == 0) {
    const int n = it - (S - 1);
    const float cinf = cstep - e;
    float rp = powf(fabsf(rho), (float)n);
    if (rho < 0.f && (n & 1)) rp = -rp;
    const float geo = (fabsf(1.f - rho) > 1e-6f)
                          ? e * rho * (1.f - rp) / (1.f - rho) : 0.f;
    out[ocOff + r] = cbase + (float)n * cinf + geo;
  }
}

extern "C" void kernel_launch(void* const* d_in, const int* in_sizes, int n_in,
                              void* d_out, int out_size, void* d_ws, size_t ws_size,
                              hipStream_t stream) {
  const float* F = (const float*)d_in[0];
  const float* f = (const float*)d_in[1];
  const float* C = (const float*)d_in[2];
  const float* c = (const float*)d_in[3];
  const int T = out_size / 24769;   // 64*128 + 64 + 128*128 + 128 + 1
  float* out = (float*)d_out;
  float* ws = (float*)d_ws;

  int okH = 0, okC = 0;
  if (ws_size >= (size_t)53520 * 4) {
    void* argsH[] = {(void*)&F, (void*)&f, (void*)&C, (void*)&c,
                     (void*)&out, (void*)&ws, (void*)&T};
    okH = (hipLaunchCooperativeKernel((void*)lqr_h, dim3(NWG), dim3(TPB),
                                      argsH, 0, stream) == hipSuccess);
    int forceC = okH ? 0 : 1;
    void* argsC[] = {(void*)&F, (void*)&f, (void*)&C, (void*)&c,
                     (void*)&out, (void*)&ws, (void*)&T, (void*)&forceC};
    okC = (hipLaunchCooperativeKernel((void*)lqr_coop, dim3(NWG), dim3(TPB),
                                      argsC, 0, stream) == hipSuccess);
  }
  const int forceF = (!okH && !okC) ? 1 : 0;
  hipLaunchKernelGGL(lqr_fb, dim3(1), dim3(TPB), 0, stream,
                     F, f, C, c, out, ws, T, forceF);
  hipLaunchKernelGGL(lqr_fill, dim3(T), dim3(256), 0, stream, ws, out, T);
}

// Round 12
// 776.448 us; speedup vs baseline: 2.5652x; 2.5652x over previous
//
#include <hip/hip_runtime.h>
#include <hip/hip_cooperative_groups.h>

namespace cg = cooperative_groups;

#define TPB 512
#define NWG 16
#define ITCAP 28

__device__ __forceinline__ float gload(const float* p) {
  return __hip_atomic_load(p, __ATOMIC_RELAXED, __HIP_MEMORY_SCOPE_AGENT);
}

__device__ __forceinline__ float4 gload4(const float* p) {
  float4 r;
  asm volatile("global_load_dwordx4 %0, %1, off sc0 sc1\n\ts_waitcnt vmcnt(0)"
               : "=&v"(r) : "v"(p) : "memory");
  return r;
}

// 64B batched agent-coherent load: 4 dwordx4 issued back-to-back, ONE waitcnt.
// Correctness-proven on-device in round 11.
__device__ __forceinline__ void gload4x4(const float* p, float4& r0, float4& r1,
                                         float4& r2, float4& r3) {
  asm volatile(
      "global_load_dwordx4 %0, %4, off sc0 sc1\n\t"
      "global_load_dwordx4 %1, %4, off offset:16 sc0 sc1\n\t"
      "global_load_dwordx4 %2, %4, off offset:32 sc0 sc1\n\t"
      "global_load_dwordx4 %3, %4, off offset:48 sc0 sc1\n\t"
      "s_waitcnt vmcnt(0)"
      : "=&v"(r0), "=&v"(r1), "=&v"(r2), "=&v"(r3)
      : "v"(p) : "memory");
}

// ---------------- block-wide reductions (512 threads = 8 waves) ----------------
__device__ __forceinline__ float blk_reduce_max(float v, float* sred, int tid) {
#pragma unroll
  for (int o = 32; o > 0; o >>= 1) v = fmaxf(v, __shfl_down(v, o));
  if ((tid & 63) == 0) sred[tid >> 6] = v;
  __syncthreads();
  if (tid == 0) {
    float m = sred[0];
#pragma unroll
    for (int w = 1; w < TPB / 64; ++w) m = fmaxf(m, sred[w]);
    sred[0] = m;
  }
  __syncthreads();
  const float r = sred[0];
  __syncthreads();
  return r;
}

__device__ __forceinline__ float blk_reduce_sum(float v, float* sred, int tid) {
#pragma unroll
  for (int o = 32; o > 0; o >>= 1) v += __shfl_down(v, o);
  if ((tid & 63) == 0) sred[tid >> 6] = v;
  __syncthreads();
  if (tid == 0) {
    float m = sred[0];
#pragma unroll
    for (int w = 1; w < TPB / 64; ++w) m += sred[w];
    sred[0] = m;
  }
  __syncthreads();
  const float r = sred[0];
  __syncthreads();
  return r;
}

__device__ __forceinline__ float dot_f4(const float* __restrict__ a,
                                        const float* __restrict__ b, int n4) {
  float acc = 0.f;
#pragma unroll 8
  for (int c = 0; c < n4; ++c) {
    const float4 x = ((const float4*)a)[c];
    const float4 y = ((const float4*)b)[c];
    acc = fmaf(x.x, y.x, fmaf(x.y, y.y, fmaf(x.z, y.z, fmaf(x.w, y.w, acc))));
  }
  return acc;
}

// ---------------- Cooperative Riccati kernel (round-10 proven + batched staging) ----------------
__global__ __launch_bounds__(TPB) void lqr_coop(
    const float* __restrict__ Fg,   // [128][192]
    const float* __restrict__ fg,   // [128]
    const float* __restrict__ Cg,   // [192][192]
    const float* __restrict__ cgv,  // [192]
    float* __restrict__ out,
    float* __restrict__ ws, int T)
{
  cg::grid_group grid = cg::this_grid();
  const int tid = threadIdx.x;
  const int w = blockIdx.x;
  const int lane = tid & 63, wv = tid >> 6;

  __shared__ __align__(16) float pool[39328];   // 157,312 B
  float* const sV   = pool;              // [128][132] staged V (row stride 132)
  float* const sQXU = pool + 16896;      // [128][68]  staged Qxu
  float* const sQUU = pool + 25600;      // [64][68]   staged Quu
  float* const sX   = pool + 29952;      // [64][68]   inv(Quu) approx (warm)
  float* const sT1  = pool + 34304;      // [64][68]   Newton scratch; overlays:
  float* const sZt  = sT1;               //   [12][132] phase-1 Zt
  float* const sM   = sT1;               //   [8][68]   phase-2 M
  float* const svv  = pool + 38656;      // [128] v (old)
  float* const sz   = svv + 128;         // [128]
  float* const sq   = sz + 128;          // [192]
  float* const sk   = sq + 192;          // [64]
  float* const sf   = sk + 64;           // [128]
  float* const sred = sf + 128;          // [16]
  float* const sS   = sred + 16;         // [8]
  float* const spz  = sS + 8;            // [8] 0=poison 1=stop

  float* const Vg   = ws + 16;           // [128][128]
  float* const vg   = Vg + 16384;        // [128]
  float* const Qg   = vg + 128;          // [192][192]
  float* const conv = Qg + 36864;        // [0..63] maxima, [64] cok
  float* const sentB = conv + 72;        // [16]
  float* const sentE = conv + 88;        // [16]

  const size_t okOff = (size_t)T * 8192;
  const size_t oVOff = okOff + (size_t)T * 64;
  const size_t ovOff = oVOff + (size_t)T * 16384;
  const size_t ocOff = ovOff + (size_t)T * 128;

  // ---- init
  if (tid < 128) sf[tid] = fg[tid];
  if (tid == 0) {
    sS[0] = 0.f; sS[1] = 0.f; sS[4] = 0.f; sS[5] = 0.85f; sS[6] = 1e30f;
    sS[7] = 0.f; spz[0] = 0.f; spz[1] = 0.f;
  }
  for (int idx = w * TPB + tid; idx < 16384; idx += TPB * NWG) {
    const int i = idx >> 7, j = idx & 127;
    Vg[idx] = Cg[i * 192 + j];
  }
  if (w == 0 && tid < 128) vg[tid] = cgv[tid];
  if (tid == 0) sentE[w] = 100.5f + (float)w;
  __syncthreads();
  __threadfence();
  grid.sync();
  if (tid < NWG) {
    if (gload(&sentE[tid]) != 100.5f + (float)tid) spz[0] = 1.f;
  }
  __syncthreads();

  int Sdone = T;
  bool converged = false;

  if (spz[0] == 0.f) {
    for (int it = 0; it < ITCAP; ++it) {
      const int rrow = T - 1 - it;

      // ===== stage V (+ old v) into LDS: 1024 x 64B chunks, 2/thread =====
#pragma unroll
      for (int qd = 0; qd < 2; ++qd) {
        const int idx = qd * TPB + tid;
        const int i = idx >> 3, c = idx & 7;   // row i, 64B chunk c
        float4 r0, r1, r2, r3;
        gload4x4(&Vg[i * 128 + c * 16], r0, r1, r2, r3);
        float* d = &sV[i * 132 + c * 16];
        *(float4*)&d[0] = r0; *(float4*)&d[4] = r1;
        *(float4*)&d[8] = r2; *(float4*)&d[12] = r3;
      }
      if (tid < 128) svv[tid] = gload(&vg[tid]);
      __syncthreads();

      // ===== phase 1 (LDS/L1 only) =====
      if (tid < 128) sz[tid] = dot_f4(&sV[tid * 132], sf, 32) + svv[tid];
      __syncthreads();
      if (w == 0) {   // fVf, fv
        float p1 = 0.f, p2 = 0.f;
        if (tid < 128) {
          const float vfk = sz[tid] - svv[tid];
          p1 = sf[tid] * vfk; p2 = sf[tid] * svv[tid];
        }
        const float fVf = blk_reduce_sum(p1, sred, tid);
        const float fv  = blk_reduce_sum(p2, sred, tid);
        if (tid == 0) { sS[2] = fVf; sS[3] = fv; }
      }
      if (tid < 192) {   // q = c + F^T z  (F via L1)
        float qa = cgv[tid];
#pragma unroll 4
        for (int k = 0; k < 128; ++k) qa = fmaf(Fg[k * 192 + tid], sz[k], qa);
        sq[tid] = qa;
      }
      {  // Zt[jl][k] = sum_m V[k][m] F[m][w*12+jl]  (V from LDS, float4)
        const int kk = lane >> 2, jj = lane & 3;
        const int k = wv * 16 + kk;
        const int j0 = w * 12;
        const float* vrow = &sV[k * 132];
        float a0 = 0.f, a1 = 0.f, a2 = 0.f;
#pragma unroll 2
        for (int m4 = 0; m4 < 32; ++m4) {
          const float4 v4 = *(const float4*)&vrow[m4 * 4];
          const int m = m4 * 4;
          a0 = fmaf(v4.x, Fg[(m + 0) * 192 + j0 + jj], a0);
          a0 = fmaf(v4.y, Fg[(m + 1) * 192 + j0 + jj], a0);
          a0 = fmaf(v4.z, Fg[(m + 2) * 192 + j0 + jj], a0);
          a0 = fmaf(v4.w, Fg[(m + 3) * 192 + j0 + jj], a0);
          a1 = fmaf(v4.x, Fg[(m + 0) * 192 + j0 + jj + 4], a1);
          a1 = fmaf(v4.y, Fg[(m + 1) * 192 + j0 + jj + 4], a1);
          a1 = fmaf(v4.z, Fg[(m + 2) * 192 + j0 + jj + 4], a1);
          a1 = fmaf(v4.w, Fg[(m + 3) * 192 + j0 + jj + 4], a1);
          a2 = fmaf(v4.x, Fg[(m + 0) * 192 + j0 + jj + 8], a2);
          a2 = fmaf(v4.y, Fg[(m + 1) * 192 + j0 + jj + 8], a2);
          a2 = fmaf(v4.z, Fg[(m + 2) * 192 + j0 + jj + 8], a2);
          a2 = fmaf(v4.w, Fg[(m + 3) * 192 + j0 + jj + 8], a2);
        }
        sZt[jj * 132 + k] = a0;
        sZt[(jj + 4) * 132 + k] = a1;
        sZt[(jj + 8) * 132 + k] = a2;
      }
      __syncthreads();
      for (int b = wv; b < 36; b += 8) {   // Q rows [w*12, w*12+12)
        const int i = (b % 12) * 16 + (lane & 15);
        const int jl = (b / 12) * 4 + (lane >> 4);
        const int jq = w * 12 + jl;
        const float* zrow = &sZt[jl * 132];
        float acc = 0.f;
#pragma unroll 2
        for (int k4 = 0; k4 < 32; ++k4) {
          const float4 z4 = *(const float4*)&zrow[k4 * 4];
          const int k = k4 * 4;
          acc = fmaf(Fg[(k + 0) * 192 + i], z4.x, acc);
          acc = fmaf(Fg[(k + 1) * 192 + i], z4.y, acc);
          acc = fmaf(Fg[(k + 2) * 192 + i], z4.z, acc);
          acc = fmaf(Fg[(k + 3) * 192 + i], z4.w, acc);
        }
        Qg[jq * 192 + i] = Cg[jq * 192 + i] + acc;
      }
      if (tid == 0) sentB[w] = (float)(it * 128 + w + 1);
      __syncthreads();
      __threadfence();
      grid.sync();   // ---- Q visible ----
      if (tid < NWG) {
        if (gload(&sentB[tid]) != (float)(it * 128 + tid + 1)) spz[0] = 1.f;
      }
      __syncthreads();
      if (spz[0] != 0.f) break;

      // ===== phase 2: stage Qxu (1 batch/thread) + Quu (256 threads) =====
      {
        const int j = tid >> 2, c = tid & 3;   // row j, 64B chunk c (of 4)
        float4 r0, r1, r2, r3;
        gload4x4(&Qg[j * 192 + 128 + c * 16], r0, r1, r2, r3);
        float* d = &sQXU[j * 68 + c * 16];
        *(float4*)&d[0] = r0; *(float4*)&d[4] = r1;
        *(float4*)&d[8] = r2; *(float4*)&d[12] = r3;
      }
      if (tid < 256) {
        const int a = tid >> 2, c = tid & 3;
        float4 r0, r1, r2, r3;
        gload4x4(&Qg[(128 + a) * 192 + 128 + c * 16], r0, r1, r2, r3);
        float* d = &sQUU[a * 68 + c * 16];
        *(float4*)&d[0] = r0; *(float4*)&d[4] = r1;
        *(float4*)&d[8] = r2; *(float4*)&d[12] = r3;
      }
      __syncthreads();

      // ---- Newton (proven fixed budget), replicated per WG ----
      {
        const int bg = tid & 7, aN = tid >> 3, b0 = bg * 8;
        if (it == 0) {
          float rsum = 0.f;
          if (tid < 64)
            for (int u = 0; u < 64; ++u) rsum += fabsf(sQUU[tid * 68 + u]);
          const float s = blk_reduce_max(rsum, sred, tid);
          const float invs = 1.f / s;
          for (int idx = tid; idx < 64 * 68; idx += TPB) {
            const int a2 = idx / 68, b2 = idx - a2 * 68;
            sX[idx] = (a2 == b2) ? invs : 0.f;
          }
          __syncthreads();
        }
        int budget = (it == 0) ? 12 : 2;
        for (int attempt = 0; attempt < 3; ++attempt) {
          for (int ns = 0; ns < budget; ++ns) {
            float t1[8] = {0, 0, 0, 0, 0, 0, 0, 0};
            for (int u = 0; u < 64; ++u) {
              const float qa = sQUU[aN * 68 + u];
              const float4 x0 = *(const float4*)&sX[u * 68 + b0];
              const float4 x1 = *(const float4*)&sX[u * 68 + b0 + 4];
              t1[0] = fmaf(qa, x0.x, t1[0]); t1[1] = fmaf(qa, x0.y, t1[1]);
              t1[2] = fmaf(qa, x0.z, t1[2]); t1[3] = fmaf(qa, x0.w, t1[3]);
              t1[4] = fmaf(qa, x1.x, t1[4]); t1[5] = fmaf(qa, x1.y, t1[5]);
              t1[6] = fmaf(qa, x1.z, t1[6]); t1[7] = fmaf(qa, x1.w, t1[7]);
            }
            *(float4*)&sT1[aN * 68 + b0]     = make_float4(t1[0], t1[1], t1[2], t1[3]);
            *(float4*)&sT1[aN * 68 + b0 + 4] = make_float4(t1[4], t1[5], t1[6], t1[7]);
            __syncthreads();
            float xn[8] = {0, 0, 0, 0, 0, 0, 0, 0};
            for (int u = 0; u < 64; ++u) {
              const float xa = sX[aN * 68 + u];
              const float4 t0 = *(const float4*)&sT1[u * 68 + b0];
              const float4 t4 = *(const float4*)&sT1[u * 68 + b0 + 4];
              xn[0] = fmaf(xa, t0.x, xn[0]); xn[1] = fmaf(xa, t0.y, xn[1]);
              xn[2] = fmaf(xa, t0.z, xn[2]); xn[3] = fmaf(xa, t0.w, xn[3]);
              xn[4] = fmaf(xa, t4.x, xn[4]); xn[5] = fmaf(xa, t4.y, xn[5]);
              xn[6] = fmaf(xa, t4.z, xn[6]); xn[7] = fmaf(xa, t4.w, xn[7]);
            }
            const float4 xo0 = *(const float4*)&sX[aN * 68 + b0];
            const float4 xo4 = *(const float4*)&sX[aN * 68 + b0 + 4];
            __syncthreads();
            *(float4*)&sX[aN * 68 + b0] =
                make_float4(2.f * xo0.x - xn[0], 2.f * xo0.y - xn[1],
                            2.f * xo0.z - xn[2], 2.f * xo0.w - xn[3]);
            *(float4*)&sX[aN * 68 + b0 + 4] =
                make_float4(2.f * xo4.x - xn[4], 2.f * xo4.y - xn[5],
                            2.f * xo4.z - xn[6], 2.f * xo4.w - xn[7]);
            __syncthreads();
          }
          float t1[8] = {0, 0, 0, 0, 0, 0, 0, 0};
          for (int u = 0; u < 64; ++u) {
            const float qa = sQUU[aN * 68 + u];
            const float4 x0 = *(const float4*)&sX[u * 68 + b0];
            const float4 x1 = *(const float4*)&sX[u * 68 + b0 + 4];
            t1[0] = fmaf(qa, x0.x, t1[0]); t1[1] = fmaf(qa, x0.y, t1[1]);
            t1[2] = fmaf(qa, x0.z, t1[2]); t1[3] = fmaf(qa, x0.w, t1[3]);
            t1[4] = fmaf(qa, x1.x, t1[4]); t1[5] = fmaf(qa, x1.y, t1[5]);
            t1[6] = fmaf(qa, x1.z, t1[6]); t1[7] = fmaf(qa, x1.w, t1[7]);
          }
          float rs_ = 0.f;
#pragma unroll
          for (int e = 0; e < 8; ++e)
            rs_ += fabsf(t1[e] - ((aN == b0 + e) ? 1.f : 0.f));
          rs_ += __shfl_xor(rs_, 1); rs_ += __shfl_xor(rs_, 2); rs_ += __shfl_xor(rs_, 4);
          if (!(rs_ == rs_)) rs_ = 1e30f;
          const float rmax = blk_reduce_max(rs_, sred, tid);
          if (rmax < 0.3f) break;
          if (attempt == 0) { budget = 3; continue; }
          {
            float rsum = 0.f;
            if (tid < 64)
              for (int u = 0; u < 64; ++u) rsum += fabsf(sQUU[tid * 68 + u]);
            const float s = blk_reduce_max(rsum, sred, tid);
            const float invs = 1.f / s;
            for (int idx = tid; idx < 64 * 68; idx += TPB) {
              const int a2 = idx / 68, b2 = idx - a2 * 68;
              sX[idx] = (a2 == b2) ? invs : 0.f;
            }
            __syncthreads();
            budget = 12;
          }
        }
      }

      // ---- k = -X qu (replicated) ----
      if (tid < 64) sk[tid] = -dot_f4(&sX[tid * 68], &sq[128], 16);
      __syncthreads();
      if (w == 0) {   // k out, cstep/const bookkeeping
        if (tid < 64) out[okOff + (size_t)rrow * 64 + tid] = sk[tid];
        float p1 = 0.f, p2 = 0.f;
        if (tid < 64) {
          const float ta = dot_f4(&sQUU[tid * 68], sk, 16);
          p1 = sk[tid] * ta; p2 = sk[tid] * sq[128 + tid];
        }
        const float kQk = blk_reduce_sum(p1, sred, tid);
        const float kqu = blk_reduce_sum(p2, sred, tid);
        if (tid == 0) {
          const float cstep_ = 0.5f * kQk + kqu + 0.5f * sS[2] + sS[3];
          const float dc = cstep_ - sS[1];
          const float dcp = sS[4];
          sS[4] = dc; sS[1] = cstep_; sS[0] += cstep_;
          out[ocOff + rrow] = sS[0];
          float r = (fabsf(dcp) > 1e-20f) ? dc / dcp : 0.85f;
          if (!(r == r)) r = 0.85f;
          r = fminf(fmaxf(r, -0.85f), 0.85f);
          const float e = -dc * r / (1.f - r);
          sS[5] = r; sS[6] = e;
          float ok = (fabsf(e) * (float)T * 0.35f <= 12.f && fabsf(dc) <= 2e-2f)
                         ? 1.f : 0.f;
          if (!(cstep_ == cstep_)) ok = 0.f;
          sS[7] = ok;
        }
      }
      {  // K out, columns [w*8, w*8+8)
        const int a = tid >> 3, jj = tid & 7, jcol = w * 8 + jj;
        const float kv = -dot_f4(&sX[a * 68], &sQXU[jcol * 68], 16);
        out[(size_t)rrow * 8192 + a * 128 + jcol] = kv;
      }
      {  // M[i][a] = dot(Qxu[w*8+i], X[a])   (sT1 dead -> sM overlay safe)
        const int i = tid >> 6, a = tid & 63;
        sM[i * 68 + a] = dot_f4(&sQXU[(w * 8 + i) * 68], &sX[a * 68], 16);
      }
      __syncthreads();
      // Vn rows [w*8, w*8+8): 256 float4 work items; old V from LDS
      float dmax = 0.f, vmax = 0.f, dvp = 0.f, mvp = 0.f, chk = 0.f;
      if (tid < 256) {
        const int i = tid >> 5, j4 = tid & 31, ig = w * 8 + i;
        const float4 qxx = gload4(&Qg[ig * 192 + j4 * 4]);
        const float4 vold = *(const float4*)&sV[ig * 132 + j4 * 4];
        const float qv[4] = {qxx.x, qxx.y, qxx.z, qxx.w};
        const float vo[4] = {vold.x, vold.y, vold.z, vold.w};
        float vn[4];
#pragma unroll
        for (int e = 0; e < 4; ++e) {
          const float acc = dot_f4(&sM[i * 68], &sQXU[(j4 * 4 + e) * 68], 16);
          vn[e] = qv[e] - acc;
          dmax = fmaxf(dmax, fabsf(vn[e] - vo[e]));
          vmax = fmaxf(vmax, fabsf(vn[e]));
          chk += vn[e];
        }
        const float4 vq = make_float4(vn[0], vn[1], vn[2], vn[3]);
        *(float4*)&Vg[ig * 128 + j4 * 4] = vq;
        *(float4*)&out[oVOff + (size_t)rrow * 16384 + ig * 128 + j4 * 4] = vq;
      }
      if (tid < 8) {   // vn rows
        const int ig = w * 8 + tid;
        const float va = sq[ig] + dot_f4(&sQXU[ig * 68], sk, 16);
        dvp = fabsf(va - svv[ig]); mvp = fabsf(va);
        chk += va;
        vg[ig] = va;
        out[ovOff + (size_t)rrow * 128 + ig] = va;
      }
      if (!(chk == chk)) { dmax = 1e30f; dvp = 1e30f; }
      const float dV_w = blk_reduce_max(dmax, sred, tid);
      const float mV_w = blk_reduce_max(vmax, sred, tid);
      const float dv_w = blk_reduce_max(dvp, sred, tid);
      const float mv_w = blk_reduce_max(mvp, sred, tid);
      if (tid == 0) {
        conv[w] = dV_w; conv[16 + w] = mV_w;
        conv[32 + w] = dv_w; conv[48 + w] = mv_w;
        if (w == 0) conv[64] = sS[7];
        sentE[w] = (float)(it * 128 + 64 + w + 1);
      }
      __syncthreads();
      __threadfence();
      grid.sync();   // ---- Vn/vn/conv visible ----
      if (tid < NWG) {
        if (gload(&sentE[tid]) != (float)(it * 128 + 64 + tid + 1)) spz[0] = 1.f;
      }
      if (tid < 16) {
        float c0 = gload(&conv[tid]), c1 = gload(&conv[16 + tid]),
              c2 = gload(&conv[32 + tid]), c3 = gload(&conv[48 + tid]);
#pragma unroll
        for (int o = 8; o > 0; o >>= 1) {
          c0 = fmaxf(c0, __shfl_down(c0, o));
          c1 = fmaxf(c1, __shfl_down(c1, o));
          c2 = fmaxf(c2, __shfl_down(c2, o));
          c3 = fmaxf(c3, __shfl_down(c3, o));
        }
        if (tid == 0) {
          const float cok = gload(&conv[64]);
          spz[1] = (it >= 3 && c0 <= 2e-3f * c1 &&
                    c2 <= 4e-3f * fmaxf(1.f, c3) && cok != 0.f) ? 1.f : 0.f;
        }
      }
      __syncthreads();
      if (spz[0] != 0.f) break;
      if (spz[1] != 0.f) { Sdone = it + 1; converged = true; break; }
    }
  }

  if (w == 0 && tid == 0) {
    ((int*)ws)[0] = Sdone;
    ws[1] = sS[1]; ws[2] = sS[0]; ws[3] = sS[5]; ws[4] = sS[6];
    ws[5] = converged ? 1.f : 0.f;
  }
}

// ---------------- Fallback: proven single-WG kernel + flag gate ----------------
__global__ __launch_bounds__(TPB) void lqr_fb(
    const float* __restrict__ Fg, const float* __restrict__ fg,
    const float* __restrict__ Cg, const float* __restrict__ cg,
    float* __restrict__ out, float* __restrict__ ws, int T, int force)
{
  if (!force && ws[5] == 1.0f) return;
  const int tid = threadIdx.x;

  __shared__ __align__(16) float pool[39584];
  float* const sV   = pool;
  float* const sQXU = pool + 16896;
  float* const sQUU = pool + 25600;
  float* const sTMP = pool + 29952;
  float* const sX   = pool + 34560;
  float* const sWT  = sQUU;
  float* const sf   = pool + 38912;
  float* const sv   = sf + 128;
  float* const sz   = sv + 128;
  float* const sq   = sz + 128;
  float* const sk   = sq + 192;
  float* const sred = sk + 64;
  float* const sS   = sred + 16;

  const size_t okOff = (size_t)T * 8192;
  const size_t oVOff = okOff + (size_t)T * 64;
  const size_t ovOff = oVOff + (size_t)T * 16384;
  const size_t ocOff = ovOff + (size_t)T * 128;

  for (int idx = tid; idx < 128 * 128; idx += TPB) {
    const int i = idx >> 7, j = idx & 127;
    sV[i * 132 + j] = Cg[i * 192 + j];
  }
  if (tid < 128) { sf[tid] = fg[tid]; sv[tid] = cg[tid]; }
  if (tid == 0) {
    sS[0] = 0.f; sS[1] = 0.f; sS[3] = 0.f;
    sS[5] = 0.85f; sS[6] = 1e30f; sS[7] = 0.f;
  }
  __syncthreads();

  int Sdone = T;

  for (int it = 0; it < T; ++it) {
    const int rrow = T - 1 - it;
    float* const outVrow = out + oVOff + (size_t)rrow * 16384;

    float wv = 0.f;
    if (tid < 128) wv = dot_f4(&sV[tid * 132], sf, 32);
    float p1 = 0.f, p2 = 0.f;
    if (tid < 128) { p1 = sf[tid] * wv; p2 = sf[tid] * sv[tid]; sz[tid] = wv + sv[tid]; }
    const float fVf = blk_reduce_sum(p1, sred, tid);
    const float fv  = blk_reduce_sum(p2, sred, tid);
    if (tid < 192) {
      float qa = cg[tid];
#pragma unroll 4
      for (int k = 0; k < 128; ++k) qa = fmaf(Fg[k * 192 + tid], sz[k], qa);
      sq[tid] = qa;
    }
    __syncthreads();

    for (int p = 0; p < 6; ++p) {
      const int j0 = p * 32;
      {
        const int jp = tid & 15, kg = tid >> 4;
        float h0[4] = {0, 0, 0, 0}, h1[4] = {0, 0, 0, 0};
        for (int m4 = 0; m4 < 32; ++m4) {
          const float2 f0 = *(const float2*)&Fg[(m4 * 4 + 0) * 192 + j0 + 2 * jp];
          const float2 f1 = *(const float2*)&Fg[(m4 * 4 + 1) * 192 + j0 + 2 * jp];
          const float2 f2 = *(const float2*)&Fg[(m4 * 4 + 2) * 192 + j0 + 2 * jp];
          const float2 f3 = *(const float2*)&Fg[(m4 * 4 + 3) * 192 + j0 + 2 * jp];
#pragma unroll
          for (int r = 0; r < 4; ++r) {
            const float4 a = *(const float4*)&sV[(kg * 4 + r) * 132 + m4 * 4];
            h0[r] = fmaf(a.x, f0.x,
                    fmaf(a.y, f1.x, fmaf(a.z, f2.x, fmaf(a.w, f3.x, h0[r]))));
            h1[r] = fmaf(a.x, f0.y,
                    fmaf(a.y, f1.y, fmaf(a.z, f2.y, fmaf(a.w, f3.y, h1[r]))));
          }
        }
        *(float4*)&sTMP[(2 * jp + 0) * 132 + kg * 4] =
            make_float4(h0[0], h0[1], h0[2], h0[3]);
        *(float4*)&sTMP[(2 * jp + 1) * 132 + kg * 4] =
            make_float4(h1[0], h1[1], h1[2], h1[3]);
        __syncthreads();
      }
      if (p < 4) {
        const int jj = tid & 31, ig = tid >> 5, i0 = ig * 12, j = j0 + jj;
        float qa[12] = {0, 0, 0, 0, 0, 0, 0, 0, 0, 0, 0, 0};
        for (int k4 = 0; k4 < 32; ++k4) {
          const float4 hb = *(const float4*)&sTMP[jj * 132 + k4 * 4];
          const float hbv[4] = {hb.x, hb.y, hb.z, hb.w};
#pragma unroll
          for (int e = 0; e < 4; ++e) {
            const int k = k4 * 4 + e;
            const float hbe = hbv[e];
            const float4 a0 = *(const float4*)&Fg[k * 192 + i0];
            const float4 a1 = *(const float4*)&Fg[k * 192 + i0 + 4];
            const float4 a2 = *(const float4*)&Fg[k * 192 + i0 + 8];
            qa[0] = fmaf(a0.x, hbe, qa[0]); qa[1] = fmaf(a0.y, hbe, qa[1]);
            qa[2] = fmaf(a0.z, hbe, qa[2]); qa[3] = fmaf(a0.w, hbe, qa[3]);
            qa[4] = fmaf(a1.x, hbe, qa[4]); qa[5] = fmaf(a1.y, hbe, qa[5]);
            qa[6] = fmaf(a1.z, hbe, qa[6]); qa[7] = fmaf(a1.w, hbe, qa[7]);
            qa[8] = fmaf(a2.x, hbe, qa[8]); qa[9] = fmaf(a2.y, hbe, qa[9]);
            qa[10] = fmaf(a2.z, hbe, qa[10]); qa[11] = fmaf(a2.w, hbe, qa[11]);
          }
        }
#pragma unroll
        for (int r = 0; r < 12; ++r) {
          const int i = i0 + r;
          const float val = Cg[i * 192 + j] + qa[r];
          if (i < 128) outVrow[i * 128 + j] = val;
          else         sQXU[j * 68 + (i - 128)] = val;
        }
        __syncthreads();
      } else {
        const int jj = tid & 31, ug = tid >> 5, u0 = ug * 4;
        float qa[4] = {0, 0, 0, 0};
        for (int k4 = 0; k4 < 32; ++k4) {
          const float4 hb = *(const float4*)&sTMP[jj * 132 + k4 * 4];
          const float hbv[4] = {hb.x, hb.y, hb.z, hb.w};
#pragma unroll
          for (int e = 0; e < 4; ++e) {
            const int k = k4 * 4 + e;
            const float hbe = hbv[e];
            const float4 a0 = *(const float4*)&Fg[k * 192 + 128 + u0];
            qa[0] = fmaf(a0.x, hbe, qa[0]); qa[1] = fmaf(a0.y, hbe, qa[1]);
            qa[2] = fmaf(a0.z, hbe, qa[2]); qa[3] = fmaf(a0.w, hbe, qa[3]);
          }
        }
#pragma unroll
        for (int r = 0; r < 4; ++r)
          sQUU[(u0 + r) * 68 + (j0 - 128 + jj)] =
              Cg[(128 + u0 + r) * 192 + j0 + jj] + qa[r];
        __syncthreads();
      }
    }

    {
      const int bg = tid & 7, aN = tid >> 3, b0 = bg * 8;
      if (it == 0) {
        float rsum = 0.f;
        if (tid < 64)
          for (int u = 0; u < 64; ++u) rsum += fabsf(sQUU[tid * 68 + u]);
        const float s = blk_reduce_max(rsum, sred, tid);
        const float invs = 1.f / s;
        for (int idx = tid; idx < 64 * 68; idx += TPB) {
          const int a2 = idx / 68, b2 = idx - a2 * 68;
          sX[idx] = (a2 == b2) ? invs : 0.f;
        }
        __syncthreads();
      }
      int budget = (it == 0) ? 12 : 2;
      for (int attempt = 0; attempt < 3; ++attempt) {
        for (int ns = 0; ns < budget; ++ns) {
          float t1[8] = {0, 0, 0, 0, 0, 0, 0, 0};
          for (int u = 0; u < 64; ++u) {
            const float qa = sQUU[aN * 68 + u];
            const float4 x0 = *(const float4*)&sX[u * 68 + b0];
            const float4 x1 = *(const float4*)&sX[u * 68 + b0 + 4];
            t1[0] = fmaf(qa, x0.x, t1[0]); t1[1] = fmaf(qa, x0.y, t1[1]);
            t1[2] = fmaf(qa, x0.z, t1[2]); t1[3] = fmaf(qa, x0.w, t1[3]);
            t1[4] = fmaf(qa, x1.x, t1[4]); t1[5] = fmaf(qa, x1.y, t1[5]);
            t1[6] = fmaf(qa, x1.z, t1[6]); t1[7] = fmaf(qa, x1.w, t1[7]);
          }
          *(float4*)&sTMP[aN * 68 + b0]     = make_float4(t1[0], t1[1], t1[2], t1[3]);
          *(float4*)&sTMP[aN * 68 + b0 + 4] = make_float4(t1[4], t1[5], t1[6], t1[7]);
          __syncthreads();
          float xn[8] = {0, 0, 0, 0, 0, 0, 0, 0};
          for (int u = 0; u < 64; ++u) {
            const float xa = sX[aN * 68 + u];
            const float4 t0 = *(const float4*)&sTMP[u * 68 + b0];
            const float4 t4 = *(const float4*)&sTMP[u * 68 + b0 + 4];
            xn[0] = fmaf(xa, t0.x, xn[0]); xn[1] = fmaf(xa, t0.y, xn[1]);
            xn[2] = fmaf(xa, t0.z, xn[2]); xn[3] = fmaf(xa, t0.w, xn[3]);
            xn[4] = fmaf(xa, t4.x, xn[4]); xn[5] = fmaf(xa, t4.y, xn[5]);
            xn[6] = fmaf(xa, t4.z, xn[6]); xn[7] = fmaf(xa, t4.w, xn[7]);
          }
          const float4 xo0 = *(const float4*)&sX[aN * 68 + b0];
          const float4 xo4 = *(const float4*)&sX[aN * 68 + b0 + 4];
          __syncthreads();
          *(float4*)&sX[aN * 68 + b0] =
              make_float4(2.f * xo0.x - xn[0], 2.f * xo0.y - xn[1],
                          2.f * xo0.z - xn[2], 2.f * xo0.w - xn[3]);
          *(float4*)&sX[aN * 68 + b0 + 4] =
              make_float4(2.f * xo4.x - xn[4], 2.f * xo4.y - xn[5],
                          2.f * xo4.z - xn[6], 2.f * xo4.w - xn[7]);
          __syncthreads();
        }
        float t1[8] = {0, 0, 0, 0, 0, 0, 0, 0};
        for (int u = 0; u < 64; ++u) {
          const float qa = sQUU[aN * 68 + u];
          const float4 x0 = *(const float4*)&sX[u * 68 + b0];
          const float4 x1 = *(const float4*)&sX[u * 68 + b0 + 4];
          t1[0] = fmaf(qa, x0.x, t1[0]); t1[1] = fmaf(qa, x0.y, t1[1]);
          t1[2] = fmaf(qa, x0.z, t1[2]); t1[3] = fmaf(qa, x0.w, t1[3]);
          t1[4] = fmaf(qa, x1.x, t1[4]); t1[5] = fmaf(qa, x1.y, t1[5]);
          t1[6] = fmaf(qa, x1.z, t1[6]); t1[7] = fmaf(qa, x1.w, t1[7]);
        }
        float rs_ = 0.f;
#pragma unroll
        for (int e = 0; e < 8; ++e)
          rs_ += fabsf(t1[e] - ((aN == b0 + e) ? 1.f : 0.f));
        rs_ += __shfl_xor(rs_, 1); rs_ += __shfl_xor(rs_, 2); rs_ += __shfl_xor(rs_, 4);
        if (!(rs_ == rs_)) rs_ = 1e30f;
        const float rmax = blk_reduce_max(rs_, sred, tid);
        if (rmax < 0.3f) break;
        if (attempt == 0) { budget = 3; continue; }
        {
          float rsum = 0.f;
          if (tid < 64)
            for (int u = 0; u < 64; ++u) rsum += fabsf(sQUU[tid * 68 + u]);
          const float s = blk_reduce_max(rsum, sred, tid);
          const float invs = 1.f / s;
          for (int idx = tid; idx < 64 * 68; idx += TPB) {
            const int a2 = idx / 68, b2 = idx - a2 * 68;
            sX[idx] = (a2 == b2) ? invs : 0.f;
          }
          __syncthreads();
          budget = 12;
        }
      }
    }

    float kQk_p = 0.f, kqu_p = 0.f;
    if (tid < 64) {
      const float ka = -dot_f4(&sX[tid * 68], &sq[128], 16);
      sk[tid] = ka;
      out[okOff + (size_t)rrow * 64 + tid] = ka;
    }
    __syncthreads();
    if (tid < 64) {
      const float ta = dot_f4(&sQUU[tid * 68], sk, 16);
      kQk_p = sk[tid] * ta;
      kqu_p = sk[tid] * sq[128 + tid];
    }
    const float kQk = blk_reduce_sum(kQk_p, sred, tid);
    const float kqu = blk_reduce_sum(kqu_p, sred, tid);
    if (tid == 0) {
      const float cstep_ = 0.5f * kQk + kqu + 0.5f * fVf + fv;
      const float dc  = cstep_ - sS[1];
      const float dcp = sS[3];
      sS[3] = dc; sS[1] = cstep_; sS[0] += cstep_;
      out[ocOff + rrow] = sS[0];
      float r = (fabsf(dcp) > 1e-20f) ? dc / dcp : 0.85f;
      if (!(r == r)) r = 0.85f;
      r = fminf(fmaxf(r, -0.85f), 0.85f);
      const float e = -dc * r / (1.f - r);
      sS[5] = r; sS[6] = e;
      sS[7] = (fabsf(e) * (float)T * 0.35f <= 12.f && fabsf(dc) <= 2e-2f) ? 1.f : 0.f;
    }
    __syncthreads();

    {
      const int ag = tid & 3, j = tid >> 2, a0 = ag * 16;
      float w[16] = {0, 0, 0, 0, 0, 0, 0, 0, 0, 0, 0, 0, 0, 0, 0, 0};
      for (int u = 0; u < 64; ++u) {
        const float qx_ = sQXU[j * 68 + u];
        const float4 x0 = *(const float4*)&sX[u * 68 + a0];
        const float4 x1 = *(const float4*)&sX[u * 68 + a0 + 4];
        const float4 x2 = *(const float4*)&sX[u * 68 + a0 + 8];
        const float4 x3 = *(const float4*)&sX[u * 68 + a0 + 12];
        const float xv[16] = {x0.x, x0.y, x0.z, x0.w, x1.x, x1.y, x1.z, x1.w,
                              x2.x, x2.y, x2.z, x2.w, x3.x, x3.y, x3.z, x3.w};
#pragma unroll
        for (int e = 0; e < 16; ++e) w[e] = fmaf(qx_, xv[e], w[e]);
      }
      *(float4*)&sWT[j * 68 + a0]      = make_float4(w[0], w[1], w[2], w[3]);
      *(float4*)&sWT[j * 68 + a0 + 4]  = make_float4(w[4], w[5], w[6], w[7]);
      *(float4*)&sWT[j * 68 + a0 + 8]  = make_float4(w[8], w[9], w[10], w[11]);
      *(float4*)&sWT[j * 68 + a0 + 12] = make_float4(w[12], w[13], w[14], w[15]);
      float* const outK = out + (size_t)rrow * 8192;
#pragma unroll
      for (int e = 0; e < 16; ++e) outK[(a0 + e) * 128 + j] = -w[e];
      __syncthreads();
    }

    {
      const int jg = tid & 3, i = tid >> 2;
      float acc[32];
#pragma unroll
      for (int r = 0; r < 32; ++r) acc[r] = 0.f;
      for (int u4 = 0; u4 < 16; ++u4) {
        const float4 qa = *(const float4*)&sQXU[i * 68 + u4 * 4];
#pragma unroll
        for (int r = 0; r < 32; ++r) {
          const float4 wb = *(const float4*)&sWT[(jg + 4 * r) * 68 + u4 * 4];
          acc[r] += qa.x * wb.x + qa.y * wb.y + qa.z * wb.z + qa.w * wb.w;
        }
      }
      float dmax = 0.f, vmax = 0.f;
#pragma unroll
      for (int r = 0; r < 32; ++r) {
        const int j = jg + 4 * r;
        const float vn_ = outVrow[i * 128 + j] - acc[r];
        dmax = fmaxf(dmax, fabsf(vn_ - sV[i * 132 + j]));
        vmax = fmaxf(vmax, fabsf(vn_));
        sV[i * 132 + j] = vn_;
        outVrow[i * 128 + j] = vn_;
      }
      float dv_p = 0.f, mv_p = 0.f;
      if (tid < 128) {
        float va = sq[tid];
        for (int u = 0; u < 64; ++u) va = fmaf(sQXU[tid * 68 + u], sk[u], va);
        dv_p = fabsf(va - sv[tid]); mv_p = fabsf(va);
        sv[tid] = va;
        out[ovOff + (size_t)rrow * 128 + tid] = va;
      }
      const float dV = blk_reduce_max(dmax, sred, tid);
      const float mV = blk_reduce_max(vmax, sred, tid);
      const float dv = blk_reduce_max(dv_p, sred, tid);
      const float mv = blk_reduce_max(mv_p, sred, tid);
      if (it >= 3 && dV <= 2e-3f * mV && dv <= 4e-3f * fmaxf(1.f, mv) &&
          sS[7] != 0.f) {
        Sdone = it + 1; break;
      }
    }
  }

  if (tid == 0) {
    ((int*)ws)[0] = Sdone;
    ws[1] = sS[1]; ws[2] = sS[0]; ws[3] = sS[5]; ws[4] = sS[6];
  }
}

// ---------------- Kernel B: replicate converged rows + geometric const ----------------
__global__ __launch_bounds__(256) void lqr_fill(
    const float* __restrict__ ws, float* __restrict__ out, int T)
{
  const int S = ((const int*)ws)[0];
  const float cstep = ws[1];
  const float cbase = ws[2];
  const float rho   = ws[3];
  const float e     = ws[4];
  const int r = blockIdx.x;
  const int it = T - 1 - r;
  if (it < S) return;
  const int rs = T - S;
  const int tid = threadIdx.x;
  const size_t okOff = (size_t)T * 8192;
  const size_t oVOff = okOff + (size_t)T * 64;
  const size_t ovOff = oVOff + (size_t)T * 16384;
  const size_t ocOff = ovOff + (size_t)T * 128;

  const float4* __restrict__ sK = (const float4*)(out + (size_t)rs * 8192);
  float4* __restrict__ dK = (float4*)(out + (size_t)r * 8192);
  for (int i = tid; i < 2048; i += 256) dK[i] = sK[i];
  const float4* __restrict__ sVr = (const float4*)(out + oVOff + (size_t)rs * 16384);
  float4* __restrict__ dV = (float4*)(out + oVOff + (size_t)r * 16384);
  for (int i = tid; i < 4096; i += 256) dV[i] = sVr[i];
  if (tid < 16)
    ((float4*)(out + okOff + (size_t)r * 64))[tid] =
        ((const float4*)(out + okOff + (size_t)rs * 64))[tid];
  if (tid >= 32 && tid < 64) {
    const int q = tid - 32;
    ((float4*)(out + ovOff + (size_t)r * 128))[q] =
        ((const float4*)(out + ovOff + (size_t)rs * 128))[q];
  }
  if (tid == 0) {
    const int n = it - (S - 1);
    const float cinf = cstep - e;
    float rp = powf(fabsf(rho), (float)n);
    if (rho < 0.f && (n & 1)) rp = -rp;
    const float geo = (fabsf(1.f - rho) > 1e-6f)
                          ? e * rho * (1.f - rp) / (1.f - rho) : 0.f;
    out[ocOff + r] = cbase + (float)n * cinf + geo;
  }
}

extern "C" void kernel_launch(void* const* d_in, const int* in_sizes, int n_in,
                              void* d_out, int out_size, void* d_ws, size_t ws_size,
                              hipStream_t stream) {
  const float* F = (const float*)d_in[0];
  const float* f = (const float*)d_in[1];
  const float* C = (const float*)d_in[2];
  const float* c = (const float*)d_in[3];
  const int T = out_size / 24769;   // 64*128 + 64 + 128*128 + 128 + 1
  float* out = (float*)d_out;
  float* ws = (float*)d_ws;

  int force = 1;
  if (ws_size >= (size_t)53520 * 4) {
    void* args[] = {(void*)&F, (void*)&f, (void*)&C, (void*)&c,
                    (void*)&out, (void*)&ws, (void*)&T};
    if (hipLaunchCooperativeKernel((void*)lqr_coop, dim3(NWG), dim3(TPB),
                                   args, 0, stream) == hipSuccess)
      force = 0;
  }
  hipLaunchKernelGGL(lqr_fb, dim3(1), dim3(TPB), 0, stream,
                     F, f, C, c, out, ws, T, force);
  hipLaunchKernelGGL(lqr_fill, dim3(T), dim3(256), 0, stream, ws, out, T);
}

// Round 13
// 610.434 us; speedup vs baseline: 3.2629x; 1.2720x over previous
//
#include <hip/hip_runtime.h>
#include <hip/hip_cooperative_groups.h>

namespace cg = cooperative_groups;

#define TPB 512
#define NWG 16
#define ITCAP 28

__device__ __forceinline__ float gload(const float* p) {
  return __hip_atomic_load(p, __ATOMIC_RELAXED, __HIP_MEMORY_SCOPE_AGENT);
}

__device__ __forceinline__ float4 gload4(const float* p) {
  float4 r;
  asm volatile("global_load_dwordx4 %0, %1, off sc0 sc1\n\ts_waitcnt vmcnt(0)"
               : "=&v"(r) : "v"(p) : "memory");
  return r;
}

__device__ __forceinline__ float2 gload2(const float* p) {
  float2 r;
  asm volatile("global_load_dwordx2 %0, %1, off sc0 sc1\n\ts_waitcnt vmcnt(0)"
               : "=&v"(r) : "v"(p) : "memory");
  return r;
}

// 64B batched agent-coherent load: 4 dwordx4 issued back-to-back, ONE waitcnt.
__device__ __forceinline__ void gload4x4(const float* p, float4& r0, float4& r1,
                                         float4& r2, float4& r3) {
  asm volatile(
      "global_load_dwordx4 %0, %4, off sc0 sc1\n\t"
      "global_load_dwordx4 %1, %4, off offset:16 sc0 sc1\n\t"
      "global_load_dwordx4 %2, %4, off offset:32 sc0 sc1\n\t"
      "global_load_dwordx4 %3, %4, off offset:48 sc0 sc1\n\t"
      "s_waitcnt vmcnt(0)"
      : "=&v"(r0), "=&v"(r1), "=&v"(r2), "=&v"(r3)
      : "v"(p) : "memory");
}

// ---------------- block-wide reductions (512 threads = 8 waves) ----------------
__device__ __forceinline__ float blk_reduce_max(float v, float* sred, int tid) {
#pragma unroll
  for (int o = 32; o > 0; o >>= 1) v = fmaxf(v, __shfl_down(v, o));
  if ((tid & 63) == 0) sred[tid >> 6] = v;
  __syncthreads();
  if (tid == 0) {
    float m = sred[0];
#pragma unroll
    for (int w = 1; w < TPB / 64; ++w) m = fmaxf(m, sred[w]);
    sred[0] = m;
  }
  __syncthreads();
  const float r = sred[0];
  __syncthreads();
  return r;
}

__device__ __forceinline__ float blk_reduce_sum(float v, float* sred, int tid) {
#pragma unroll
  for (int o = 32; o > 0; o >>= 1) v += __shfl_down(v, o);
  if ((tid & 63) == 0) sred[tid >> 6] = v;
  __syncthreads();
  if (tid == 0) {
    float m = sred[0];
#pragma unroll
    for (int w = 1; w < TPB / 64; ++w) m += sred[w];
    sred[0] = m;
  }
  __syncthreads();
  const float r = sred[0];
  __syncthreads();
  return r;
}

__device__ __forceinline__ float dot_f4(const float* __restrict__ a,
                                        const float* __restrict__ b, int n4) {
  float acc = 0.f;
#pragma unroll 8
  for (int c = 0; c < n4; ++c) {
    const float4 x = ((const float4*)a)[c];
    const float4 y = ((const float4*)b)[c];
    acc = fmaf(x.x, y.x, fmaf(x.y, y.y, fmaf(x.z, y.z, fmaf(x.w, y.w, acc))));
  }
  return acc;
}

// ---------------- Cooperative Riccati kernel ----------------
// r10/r12 proven structure. Changes: Newton warm budget 2->1 (verify kept),
// Vn remapped to all 512 threads (2 elems/thread), looser stop gates.
__global__ __launch_bounds__(TPB) void lqr_coop(
    const float* __restrict__ Fg,   // [128][192]
    const float* __restrict__ fg,   // [128]
    const float* __restrict__ Cg,   // [192][192]
    const float* __restrict__ cgv,  // [192]
    float* __restrict__ out,
    float* __restrict__ ws, int T)
{
  cg::grid_group grid = cg::this_grid();
  const int tid = threadIdx.x;
  const int w = blockIdx.x;
  const int lane = tid & 63, wv = tid >> 6;

  __shared__ __align__(16) float pool[39328];   // 157,312 B
  float* const sV   = pool;              // [128][132] staged V
  float* const sQXU = pool + 16896;      // [128][68]  staged Qxu
  float* const sQUU = pool + 25600;      // [64][68]   staged Quu
  float* const sX   = pool + 29952;      // [64][68]   inv(Quu) approx (warm)
  float* const sT1  = pool + 34304;      // [64][68]   Newton scratch; overlays:
  float* const sZt  = sT1;               //   [12][132] phase-1 Zt
  float* const sM   = sT1;               //   [8][68]   phase-2 M
  float* const svv  = pool + 38656;      // [128]
  float* const sz   = svv + 128;         // [128]
  float* const sq   = sz + 128;          // [192]
  float* const sk   = sq + 192;          // [64]
  float* const sf   = sk + 64;           // [128]
  float* const sred = sf + 128;          // [16]
  float* const sS   = sred + 16;         // [8]
  float* const spz  = sS + 8;            // [8] 0=poison 1=stop

  float* const Vg   = ws + 16;           // [128][128]
  float* const vg   = Vg + 16384;        // [128]
  float* const Qg   = vg + 128;          // [192][192]
  float* const conv = Qg + 36864;        // [0..63] maxima, [64] cok
  float* const sentB = conv + 72;        // [16]
  float* const sentE = conv + 88;        // [16]

  const size_t okOff = (size_t)T * 8192;
  const size_t oVOff = okOff + (size_t)T * 64;
  const size_t ovOff = oVOff + (size_t)T * 16384;
  const size_t ocOff = ovOff + (size_t)T * 128;

  // ---- init
  if (tid < 128) sf[tid] = fg[tid];
  if (tid == 0) {
    sS[0] = 0.f; sS[1] = 0.f; sS[4] = 0.f; sS[5] = 0.85f; sS[6] = 1e30f;
    sS[7] = 0.f; spz[0] = 0.f; spz[1] = 0.f;
  }
  for (int idx = w * TPB + tid; idx < 16384; idx += TPB * NWG) {
    const int i = idx >> 7, j = idx & 127;
    Vg[idx] = Cg[i * 192 + j];
  }
  if (w == 0 && tid < 128) vg[tid] = cgv[tid];
  if (tid == 0) sentE[w] = 100.5f + (float)w;
  __syncthreads();
  __threadfence();
  grid.sync();
  if (tid < NWG) {
    if (gload(&sentE[tid]) != 100.5f + (float)tid) spz[0] = 1.f;
  }
  __syncthreads();

  int Sdone = T;
  bool converged = false;

  if (spz[0] == 0.f) {
    for (int it = 0; it < ITCAP; ++it) {
      const int rrow = T - 1 - it;

      // ===== stage V (+ old v) into LDS =====
#pragma unroll
      for (int qd = 0; qd < 2; ++qd) {
        const int idx = qd * TPB + tid;
        const int i = idx >> 3, c = idx & 7;
        float4 r0, r1, r2, r3;
        gload4x4(&Vg[i * 128 + c * 16], r0, r1, r2, r3);
        float* d = &sV[i * 132 + c * 16];
        *(float4*)&d[0] = r0; *(float4*)&d[4] = r1;
        *(float4*)&d[8] = r2; *(float4*)&d[12] = r3;
      }
      if (tid < 128) svv[tid] = gload(&vg[tid]);
      __syncthreads();

      // ===== phase 1 (LDS/L1 only) =====
      if (tid < 128) sz[tid] = dot_f4(&sV[tid * 132], sf, 32) + svv[tid];
      __syncthreads();
      if (w == 0) {   // fVf, fv
        float p1 = 0.f, p2 = 0.f;
        if (tid < 128) {
          const float vfk = sz[tid] - svv[tid];
          p1 = sf[tid] * vfk; p2 = sf[tid] * svv[tid];
        }
        const float fVf = blk_reduce_sum(p1, sred, tid);
        const float fv  = blk_reduce_sum(p2, sred, tid);
        if (tid == 0) { sS[2] = fVf; sS[3] = fv; }
      }
      if (tid < 192) {   // q = c + F^T z
        float qa = cgv[tid];
#pragma unroll 4
        for (int k = 0; k < 128; ++k) qa = fmaf(Fg[k * 192 + tid], sz[k], qa);
        sq[tid] = qa;
      }
      {  // Zt[jl][k] = sum_m V[k][m] F[m][w*12+jl]
        const int kk = lane >> 2, jj = lane & 3;
        const int k = wv * 16 + kk;
        const int j0 = w * 12;
        const float* vrow = &sV[k * 132];
        float a0 = 0.f, a1 = 0.f, a2 = 0.f;
#pragma unroll 2
        for (int m4 = 0; m4 < 32; ++m4) {
          const float4 v4 = *(const float4*)&vrow[m4 * 4];
          const int m = m4 * 4;
          a0 = fmaf(v4.x, Fg[(m + 0) * 192 + j0 + jj], a0);
          a0 = fmaf(v4.y, Fg[(m + 1) * 192 + j0 + jj], a0);
          a0 = fmaf(v4.z, Fg[(m + 2) * 192 + j0 + jj], a0);
          a0 = fmaf(v4.w, Fg[(m + 3) * 192 + j0 + jj], a0);
          a1 = fmaf(v4.x, Fg[(m + 0) * 192 + j0 + jj + 4], a1);
          a1 = fmaf(v4.y, Fg[(m + 1) * 192 + j0 + jj + 4], a1);
          a1 = fmaf(v4.z, Fg[(m + 2) * 192 + j0 + jj + 4], a1);
          a1 = fmaf(v4.w, Fg[(m + 3) * 192 + j0 + jj + 4], a1);
          a2 = fmaf(v4.x, Fg[(m + 0) * 192 + j0 + jj + 8], a2);
          a2 = fmaf(v4.y, Fg[(m + 1) * 192 + j0 + jj + 8], a2);
          a2 = fmaf(v4.z, Fg[(m + 2) * 192 + j0 + jj + 8], a2);
          a2 = fmaf(v4.w, Fg[(m + 3) * 192 + j0 + jj + 8], a2);
        }
        sZt[jj * 132 + k] = a0;
        sZt[(jj + 4) * 132 + k] = a1;
        sZt[(jj + 8) * 132 + k] = a2;
      }
      __syncthreads();
      for (int b = wv; b < 36; b += 8) {   // Q rows [w*12, w*12+12)
        const int i = (b % 12) * 16 + (lane & 15);
        const int jl = (b / 12) * 4 + (lane >> 4);
        const int jq = w * 12 + jl;
        const float* zrow = &sZt[jl * 132];
        float acc = 0.f;
#pragma unroll 2
        for (int k4 = 0; k4 < 32; ++k4) {
          const float4 z4 = *(const float4*)&zrow[k4 * 4];
          const int k = k4 * 4;
          acc = fmaf(Fg[(k + 0) * 192 + i], z4.x, acc);
          acc = fmaf(Fg[(k + 1) * 192 + i], z4.y, acc);
          acc = fmaf(Fg[(k + 2) * 192 + i], z4.z, acc);
          acc = fmaf(Fg[(k + 3) * 192 + i], z4.w, acc);
        }
        Qg[jq * 192 + i] = Cg[jq * 192 + i] + acc;
      }
      if (tid == 0) sentB[w] = (float)(it * 128 + w + 1);
      __syncthreads();
      __threadfence();
      grid.sync();   // ---- Q visible ----
      if (tid < NWG) {
        if (gload(&sentB[tid]) != (float)(it * 128 + tid + 1)) spz[0] = 1.f;
      }
      __syncthreads();
      if (spz[0] != 0.f) break;

      // ===== phase 2: stage Qxu + Quu =====
      {
        const int j = tid >> 2, c = tid & 3;
        float4 r0, r1, r2, r3;
        gload4x4(&Qg[j * 192 + 128 + c * 16], r0, r1, r2, r3);
        float* d = &sQXU[j * 68 + c * 16];
        *(float4*)&d[0] = r0; *(float4*)&d[4] = r1;
        *(float4*)&d[8] = r2; *(float4*)&d[12] = r3;
      }
      if (tid < 256) {
        const int a = tid >> 2, c = tid & 3;
        float4 r0, r1, r2, r3;
        gload4x4(&Qg[(128 + a) * 192 + 128 + c * 16], r0, r1, r2, r3);
        float* d = &sQUU[a * 68 + c * 16];
        *(float4*)&d[0] = r0; *(float4*)&d[4] = r1;
        *(float4*)&d[8] = r2; *(float4*)&d[12] = r3;
      }
      __syncthreads();

      // ---- Newton: 1 warm blind step + verify (escalation kept) ----
      {
        const int bg = tid & 7, aN = tid >> 3, b0 = bg * 8;
        if (it == 0) {
          float rsum = 0.f;
          if (tid < 64)
            for (int u = 0; u < 64; ++u) rsum += fabsf(sQUU[tid * 68 + u]);
          const float s = blk_reduce_max(rsum, sred, tid);
          const float invs = 1.f / s;
          for (int idx = tid; idx < 64 * 68; idx += TPB) {
            const int a2 = idx / 68, b2 = idx - a2 * 68;
            sX[idx] = (a2 == b2) ? invs : 0.f;
          }
          __syncthreads();
        }
        int budget = (it == 0) ? 12 : 1;
        for (int attempt = 0; attempt < 3; ++attempt) {
          for (int ns = 0; ns < budget; ++ns) {
            float t1[8] = {0, 0, 0, 0, 0, 0, 0, 0};
            for (int u = 0; u < 64; ++u) {
              const float qa = sQUU[aN * 68 + u];
              const float4 x0 = *(const float4*)&sX[u * 68 + b0];
              const float4 x1 = *(const float4*)&sX[u * 68 + b0 + 4];
              t1[0] = fmaf(qa, x0.x, t1[0]); t1[1] = fmaf(qa, x0.y, t1[1]);
              t1[2] = fmaf(qa, x0.z, t1[2]); t1[3] = fmaf(qa, x0.w, t1[3]);
              t1[4] = fmaf(qa, x1.x, t1[4]); t1[5] = fmaf(qa, x1.y, t1[5]);
              t1[6] = fmaf(qa, x1.z, t1[6]); t1[7] = fmaf(qa, x1.w, t1[7]);
            }
            *(float4*)&sT1[aN * 68 + b0]     = make_float4(t1[0], t1[1], t1[2], t1[3]);
            *(float4*)&sT1[aN * 68 + b0 + 4] = make_float4(t1[4], t1[5], t1[6], t1[7]);
            __syncthreads();
            float xn[8] = {0, 0, 0, 0, 0, 0, 0, 0};
            for (int u = 0; u < 64; ++u) {
              const float xa = sX[aN * 68 + u];
              const float4 t0 = *(const float4*)&sT1[u * 68 + b0];
              const float4 t4 = *(const float4*)&sT1[u * 68 + b0 + 4];
              xn[0] = fmaf(xa, t0.x, xn[0]); xn[1] = fmaf(xa, t0.y, xn[1]);
              xn[2] = fmaf(xa, t0.z, xn[2]); xn[3] = fmaf(xa, t0.w, xn[3]);
              xn[4] = fmaf(xa, t4.x, xn[4]); xn[5] = fmaf(xa, t4.y, xn[5]);
              xn[6] = fmaf(xa, t4.z, xn[6]); xn[7] = fmaf(xa, t4.w, xn[7]);
            }
            const float4 xo0 = *(const float4*)&sX[aN * 68 + b0];
            const float4 xo4 = *(const float4*)&sX[aN * 68 + b0 + 4];
            __syncthreads();
            *(float4*)&sX[aN * 68 + b0] =
                make_float4(2.f * xo0.x - xn[0], 2.f * xo0.y - xn[1],
                            2.f * xo0.z - xn[2], 2.f * xo0.w - xn[3]);
            *(float4*)&sX[aN * 68 + b0 + 4] =
                make_float4(2.f * xo4.x - xn[4], 2.f * xo4.y - xn[5],
                            2.f * xo4.z - xn[6], 2.f * xo4.w - xn[7]);
            __syncthreads();
          }
          // verify (1 matmul + exact inf-norm)
          float t1[8] = {0, 0, 0, 0, 0, 0, 0, 0};
          for (int u = 0; u < 64; ++u) {
            const float qa = sQUU[aN * 68 + u];
            const float4 x0 = *(const float4*)&sX[u * 68 + b0];
            const float4 x1 = *(const float4*)&sX[u * 68 + b0 + 4];
            t1[0] = fmaf(qa, x0.x, t1[0]); t1[1] = fmaf(qa, x0.y, t1[1]);
            t1[2] = fmaf(qa, x0.z, t1[2]); t1[3] = fmaf(qa, x0.w, t1[3]);
            t1[4] = fmaf(qa, x1.x, t1[4]); t1[5] = fmaf(qa, x1.y, t1[5]);
            t1[6] = fmaf(qa, x1.z, t1[6]); t1[7] = fmaf(qa, x1.w, t1[7]);
          }
          float rs_ = 0.f;
#pragma unroll
          for (int e = 0; e < 8; ++e)
            rs_ += fabsf(t1[e] - ((aN == b0 + e) ? 1.f : 0.f));
          rs_ += __shfl_xor(rs_, 1); rs_ += __shfl_xor(rs_, 2); rs_ += __shfl_xor(rs_, 4);
          if (!(rs_ == rs_)) rs_ = 1e30f;
          const float rmax = blk_reduce_max(rs_, sred, tid);
          if (rmax < 0.3f) break;
          if (attempt == 0) { budget = 3; continue; }
          {
            float rsum = 0.f;
            if (tid < 64)
              for (int u = 0; u < 64; ++u) rsum += fabsf(sQUU[tid * 68 + u]);
            const float s = blk_reduce_max(rsum, sred, tid);
            const float invs = 1.f / s;
            for (int idx = tid; idx < 64 * 68; idx += TPB) {
              const int a2 = idx / 68, b2 = idx - a2 * 68;
              sX[idx] = (a2 == b2) ? invs : 0.f;
            }
            __syncthreads();
            budget = 12;
          }
        }
      }

      // ---- k = -X qu (replicated) ----
      if (tid < 64) sk[tid] = -dot_f4(&sX[tid * 68], &sq[128], 16);
      __syncthreads();
      if (w == 0) {   // k out, cstep/const bookkeeping
        if (tid < 64) out[okOff + (size_t)rrow * 64 + tid] = sk[tid];
        float p1 = 0.f, p2 = 0.f;
        if (tid < 64) {
          const float ta = dot_f4(&sQUU[tid * 68], sk, 16);
          p1 = sk[tid] * ta; p2 = sk[tid] * sq[128 + tid];
        }
        const float kQk = blk_reduce_sum(p1, sred, tid);
        const float kqu = blk_reduce_sum(p2, sred, tid);
        if (tid == 0) {
          const float cstep_ = 0.5f * kQk + kqu + 0.5f * sS[2] + sS[3];
          const float dc = cstep_ - sS[1];
          const float dcp = sS[4];
          sS[4] = dc; sS[1] = cstep_; sS[0] += cstep_;
          out[ocOff + rrow] = sS[0];
          float r = (fabsf(dcp) > 1e-20f) ? dc / dcp : 0.85f;
          if (!(r == r)) r = 0.85f;
          r = fminf(fmaxf(r, -0.85f), 0.85f);
          const float e = -dc * r / (1.f - r);
          sS[5] = r; sS[6] = e;
          float ok = (fabsf(e) * (float)T * 0.35f <= 20.f && fabsf(dc) <= 5e-2f)
                         ? 1.f : 0.f;
          if (!(cstep_ == cstep_)) ok = 0.f;
          sS[7] = ok;
        }
      }
      {  // K out, columns [w*8, w*8+8)
        const int a = tid >> 3, jj = tid & 7, jcol = w * 8 + jj;
        const float kv = -dot_f4(&sX[a * 68], &sQXU[jcol * 68], 16);
        out[(size_t)rrow * 8192 + a * 128 + jcol] = kv;
      }
      {  // M[i][a] = dot(Qxu[w*8+i], X[a])   (sT1 dead -> sM overlay safe)
        const int i = tid >> 6, a = tid & 63;
        sM[i * 68 + a] = dot_f4(&sQXU[(w * 8 + i) * 68], &sX[a * 68], 16);
      }
      __syncthreads();
      // Vn rows [w*8, w*8+8): ALL 512 threads, 2 elems each
      float dmax = 0.f, vmax = 0.f, dvp = 0.f, mvp = 0.f, chk = 0.f;
      {
        const int i = tid >> 6, j2 = tid & 63, ig = w * 8 + i;  // j = 2*j2, 2*j2+1
        const float2 qxx = gload2(&Qg[ig * 192 + j2 * 2]);
        const float2 vold = *(const float2*)&sV[ig * 132 + j2 * 2];
        const float a0 = dot_f4(&sM[i * 68], &sQXU[(j2 * 2 + 0) * 68], 16);
        const float a1 = dot_f4(&sM[i * 68], &sQXU[(j2 * 2 + 1) * 68], 16);
        const float vn0 = qxx.x - a0, vn1 = qxx.y - a1;
        dmax = fmaxf(fabsf(vn0 - vold.x), fabsf(vn1 - vold.y));
        vmax = fmaxf(fabsf(vn0), fabsf(vn1));
        chk += vn0 + vn1;
        const float2 vq = make_float2(vn0, vn1);
        *(float2*)&Vg[ig * 128 + j2 * 2] = vq;
        *(float2*)&out[oVOff + (size_t)rrow * 16384 + ig * 128 + j2 * 2] = vq;
      }
      if (tid < 8) {   // vn rows
        const int ig = w * 8 + tid;
        const float va = sq[ig] + dot_f4(&sQXU[ig * 68], sk, 16);
        dvp = fabsf(va - svv[ig]); mvp = fabsf(va);
        chk += va;
        vg[ig] = va;
        out[ovOff + (size_t)rrow * 128 + ig] = va;
      }
      if (!(chk == chk)) { dmax = 1e30f; dvp = 1e30f; }
      const float dV_w = blk_reduce_max(dmax, sred, tid);
      const float mV_w = blk_reduce_max(vmax, sred, tid);
      const float dv_w = blk_reduce_max(dvp, sred, tid);
      const float mv_w = blk_reduce_max(mvp, sred, tid);
      if (tid == 0) {
        conv[w] = dV_w; conv[16 + w] = mV_w;
        conv[32 + w] = dv_w; conv[48 + w] = mv_w;
        if (w == 0) conv[64] = sS[7];
        sentE[w] = (float)(it * 128 + 64 + w + 1);
      }
      __syncthreads();
      __threadfence();
      grid.sync();   // ---- Vn/vn/conv visible ----
      if (tid < NWG) {
        if (gload(&sentE[tid]) != (float)(it * 128 + 64 + tid + 1)) spz[0] = 1.f;
      }
      if (tid < 16) {
        float c0 = gload(&conv[tid]), c1 = gload(&conv[16 + tid]),
              c2 = gload(&conv[32 + tid]), c3 = gload(&conv[48 + tid]);
#pragma unroll
        for (int o = 8; o > 0; o >>= 1) {
          c0 = fmaxf(c0, __shfl_down(c0, o));
          c1 = fmaxf(c1, __shfl_down(c1, o));
          c2 = fmaxf(c2, __shfl_down(c2, o));
          c3 = fmaxf(c3, __shfl_down(c3, o));
        }
        if (tid == 0) {
          const float cok = gload(&conv[64]);
          spz[1] = (it >= 3 && c0 <= 4e-3f * c1 &&
                    c2 <= 8e-3f * fmaxf(1.f, c3) && cok != 0.f) ? 1.f : 0.f;
        }
      }
      __syncthreads();
      if (spz[0] != 0.f) break;
      if (spz[1] != 0.f) { Sdone = it + 1; converged = true; break; }
    }
  }

  if (w == 0 && tid == 0) {
    ((int*)ws)[0] = Sdone;
    ws[1] = sS[1]; ws[2] = sS[0]; ws[3] = sS[5]; ws[4] = sS[6];
    ws[5] = converged ? 1.f : 0.f;
  }
}

// ---------------- Fallback: proven single-WG kernel + flag gate ----------------
__global__ __launch_bounds__(TPB) void lqr_fb(
    const float* __restrict__ Fg, const float* __restrict__ fg,
    const float* __restrict__ Cg, const float* __restrict__ cg,
    float* __restrict__ out, float* __restrict__ ws, int T, int force)
{
  if (!force && ws[5] == 1.0f) return;
  const int tid = threadIdx.x;

  __shared__ __align__(16) float pool[39584];
  float* const sV   = pool;
  float* const sQXU = pool + 16896;
  float* const sQUU = pool + 25600;
  float* const sTMP = pool + 29952;
  float* const sX   = pool + 34560;
  float* const sWT  = sQUU;
  float* const sf   = pool + 38912;
  float* const sv   = sf + 128;
  float* const sz   = sv + 128;
  float* const sq   = sz + 128;
  float* const sk   = sq + 192;
  float* const sred = sk + 64;
  float* const sS   = sred + 16;

  const size_t okOff = (size_t)T * 8192;
  const size_t oVOff = okOff + (size_t)T * 64;
  const size_t ovOff = oVOff + (size_t)T * 16384;
  const size_t ocOff = ovOff + (size_t)T * 128;

  for (int idx = tid; idx < 128 * 128; idx += TPB) {
    const int i = idx >> 7, j = idx & 127;
    sV[i * 132 + j] = Cg[i * 192 + j];
  }
  if (tid < 128) { sf[tid] = fg[tid]; sv[tid] = cg[tid]; }
  if (tid == 0) {
    sS[0] = 0.f; sS[1] = 0.f; sS[3] = 0.f;
    sS[5] = 0.85f; sS[6] = 1e30f; sS[7] = 0.f;
  }
  __syncthreads();

  int Sdone = T;

  for (int it = 0; it < T; ++it) {
    const int rrow = T - 1 - it;
    float* const outVrow = out + oVOff + (size_t)rrow * 16384;

    float wv = 0.f;
    if (tid < 128) wv = dot_f4(&sV[tid * 132], sf, 32);
    float p1 = 0.f, p2 = 0.f;
    if (tid < 128) { p1 = sf[tid] * wv; p2 = sf[tid] * sv[tid]; sz[tid] = wv + sv[tid]; }
    const float fVf = blk_reduce_sum(p1, sred, tid);
    const float fv  = blk_reduce_sum(p2, sred, tid);
    if (tid < 192) {
      float qa = cg[tid];
#pragma unroll 4
      for (int k = 0; k < 128; ++k) qa = fmaf(Fg[k * 192 + tid], sz[k], qa);
      sq[tid] = qa;
    }
    __syncthreads();

    for (int p = 0; p < 6; ++p) {
      const int j0 = p * 32;
      {
        const int jp = tid & 15, kg = tid >> 4;
        float h0[4] = {0, 0, 0, 0}, h1[4] = {0, 0, 0, 0};
        for (int m4 = 0; m4 < 32; ++m4) {
          const float2 f0 = *(const float2*)&Fg[(m4 * 4 + 0) * 192 + j0 + 2 * jp];
          const float2 f1 = *(const float2*)&Fg[(m4 * 4 + 1) * 192 + j0 + 2 * jp];
          const float2 f2 = *(const float2*)&Fg[(m4 * 4 + 2) * 192 + j0 + 2 * jp];
          const float2 f3 = *(const float2*)&Fg[(m4 * 4 + 3) * 192 + j0 + 2 * jp];
#pragma unroll
          for (int r = 0; r < 4; ++r) {
            const float4 a = *(const float4*)&sV[(kg * 4 + r) * 132 + m4 * 4];
            h0[r] = fmaf(a.x, f0.x,
                    fmaf(a.y, f1.x, fmaf(a.z, f2.x, fmaf(a.w, f3.x, h0[r]))));
            h1[r] = fmaf(a.x, f0.y,
                    fmaf(a.y, f1.y, fmaf(a.z, f2.y, fmaf(a.w, f3.y, h1[r]))));
          }
        }
        *(float4*)&sTMP[(2 * jp + 0) * 132 + kg * 4] =
            make_float4(h0[0], h0[1], h0[2], h0[3]);
        *(float4*)&sTMP[(2 * jp + 1) * 132 + kg * 4] =
            make_float4(h1[0], h1[1], h1[2], h1[3]);
        __syncthreads();
      }
      if (p < 4) {
        const int jj = tid & 31, ig = tid >> 5, i0 = ig * 12, j = j0 + jj;
        float qa[12] = {0, 0, 0, 0, 0, 0, 0, 0, 0, 0, 0, 0};
        for (int k4 = 0; k4 < 32; ++k4) {
          const float4 hb = *(const float4*)&sTMP[jj * 132 + k4 * 4];
          const float hbv[4] = {hb.x, hb.y, hb.z, hb.w};
#pragma unroll
          for (int e = 0; e < 4; ++e) {
            const int k = k4 * 4 + e;
            const float hbe = hbv[e];
            const float4 a0 = *(const float4*)&Fg[k * 192 + i0];
            const float4 a1 = *(const float4*)&Fg[k * 192 + i0 + 4];
            const float4 a2 = *(const float4*)&Fg[k * 192 + i0 + 8];
            qa[0] = fmaf(a0.x, hbe, qa[0]); qa[1] = fmaf(a0.y, hbe, qa[1]);
            qa[2] = fmaf(a0.z, hbe, qa[2]); qa[3] = fmaf(a0.w, hbe, qa[3]);
            qa[4] = fmaf(a1.x, hbe, qa[4]); qa[5] = fmaf(a1.y, hbe, qa[5]);
            qa[6] = fmaf(a1.z, hbe, qa[6]); qa[7] = fmaf(a1.w, hbe, qa[7]);
            qa[8] = fmaf(a2.x, hbe, qa[8]); qa[9] = fmaf(a2.y, hbe, qa[9]);
            qa[10] = fmaf(a2.z, hbe, qa[10]); qa[11] = fmaf(a2.w, hbe, qa[11]);
          }
        }
#pragma unroll
        for (int r = 0; r < 12; ++r) {
          const int i = i0 + r;
          const float val = Cg[i * 192 + j] + qa[r];
          if (i < 128) outVrow[i * 128 + j] = val;
          else         sQXU[j * 68 + (i - 128)] = val;
        }
        __syncthreads();
      } else {
        const int jj = tid & 31, ug = tid >> 5, u0 = ug * 4;
        float qa[4] = {0, 0, 0, 0};
        for (int k4 = 0; k4 < 32; ++k4) {
          const float4 hb = *(const float4*)&sTMP[jj * 132 + k4 * 4];
          const float hbv[4] = {hb.x, hb.y, hb.z, hb.w};
#pragma unroll
          for (int e = 0; e < 4; ++e) {
            const int k = k4 * 4 + e;
            const float hbe = hbv[e];
            const float4 a0 = *(const float4*)&Fg[k * 192 + 128 + u0];
            qa[0] = fmaf(a0.x, hbe, qa[0]); qa[1] = fmaf(a0.y, hbe, qa[1]);
            qa[2] = fmaf(a0.z, hbe, qa[2]); qa[3] = fmaf(a0.w, hbe, qa[3]);
          }
        }
#pragma unroll
        for (int r = 0; r < 4; ++r)
          sQUU[(u0 + r) * 68 + (j0 - 128 + jj)] =
              Cg[(128 + u0 + r) * 192 + j0 + jj] + qa[r];
        __syncthreads();
      }
    }

    {
      const int bg = tid & 7, aN = tid >> 3, b0 = bg * 8;
      if (it == 0) {
        float rsum = 0.f;
        if (tid < 64)
          for (int u = 0; u < 64; ++u) rsum += fabsf(sQUU[tid * 68 + u]);
        const float s = blk_reduce_max(rsum, sred, tid);
        const float invs = 1.f / s;
        for (int idx = tid; idx < 64 * 68; idx += TPB) {
          const int a2 = idx / 68, b2 = idx - a2 * 68;
          sX[idx] = (a2 == b2) ? invs : 0.f;
        }
        __syncthreads();
      }
      int budget = (it == 0) ? 12 : 2;
      for (int attempt = 0; attempt < 3; ++attempt) {
        for (int ns = 0; ns < budget; ++ns) {
          float t1[8] = {0, 0, 0, 0, 0, 0, 0, 0};
          for (int u = 0; u < 64; ++u) {
            const float qa = sQUU[aN * 68 + u];
            const float4 x0 = *(const float4*)&sX[u * 68 + b0];
            const float4 x1 = *(const float4*)&sX[u * 68 + b0 + 4];
            t1[0] = fmaf(qa, x0.x, t1[0]); t1[1] = fmaf(qa, x0.y, t1[1]);
            t1[2] = fmaf(qa, x0.z, t1[2]); t1[3] = fmaf(qa, x0.w, t1[3]);
            t1[4] = fmaf(qa, x1.x, t1[4]); t1[5] = fmaf(qa, x1.y, t1[5]);
            t1[6] = fmaf(qa, x1.z, t1[6]); t1[7] = fmaf(qa, x1.w, t1[7]);
          }
          *(float4*)&sTMP[aN * 68 + b0]     = make_float4(t1[0], t1[1], t1[2], t1[3]);
          *(float4*)&sTMP[aN * 68 + b0 + 4] = make_float4(t1[4], t1[5], t1[6], t1[7]);
          __syncthreads();
          float xn[8] = {0, 0, 0, 0, 0, 0, 0, 0};
          for (int u = 0; u < 64; ++u) {
            const float xa = sX[aN * 68 + u];
            const float4 t0 = *(const float4*)&sTMP[u * 68 + b0];
            const float4 t4 = *(const float4*)&sTMP[u * 68 + b0 + 4];
            xn[0] = fmaf(xa, t0.x, xn[0]); xn[1] = fmaf(xa, t0.y, xn[1]);
            xn[2] = fmaf(xa, t0.z, xn[2]); xn[3] = fmaf(xa, t0.w, xn[3]);
            xn[4] = fmaf(xa, t4.x, xn[4]); xn[5] = fmaf(xa, t4.y, xn[5]);
            xn[6] = fmaf(xa, t4.z, xn[6]); xn[7] = fmaf(xa, t4.w, xn[7]);
          }
          const float4 xo0 = *(const float4*)&sX[aN * 68 + b0];
          const float4 xo4 = *(const float4*)&sX[aN * 68 + b0 + 4];
          __syncthreads();
          *(float4*)&sX[aN * 68 + b0] =
              make_float4(2.f * xo0.x - xn[0], 2.f * xo0.y - xn[1],
                          2.f * xo0.z - xn[2], 2.f * xo0.w - xn[3]);
          *(float4*)&sX[aN * 68 + b0 + 4] =
              make_float4(2.f * xo4.x - xn[4], 2.f * xo4.y - xn[5],
                          2.f * xo4.z - xn[6], 2.f * xo4.w - xn[7]);
          __syncthreads();
        }
        float t1[8] = {0, 0, 0, 0, 0, 0, 0, 0};
        for (int u = 0; u < 64; ++u) {
          const float qa = sQUU[aN * 68 + u];
          const float4 x0 = *(const float4*)&sX[u * 68 + b0];
          const float4 x1 = *(const float4*)&sX[u * 68 + b0 + 4];
          t1[0] = fmaf(qa, x0.x, t1[0]); t1[1] = fmaf(qa, x0.y, t1[1]);
          t1[2] = fmaf(qa, x0.z, t1[2]); t1[3] = fmaf(qa, x0.w, t1[3]);
          t1[4] = fmaf(qa, x1.x, t1[4]); t1[5] = fmaf(qa, x1.y, t1[5]);
          t1[6] = fmaf(qa, x1.z, t1[6]); t1[7] = fmaf(qa, x1.w, t1[7]);
        }
        float rs_ = 0.f;
#pragma unroll
        for (int e = 0; e < 8; ++e)
          rs_ += fabsf(t1[e] - ((aN == b0 + e) ? 1.f : 0.f));
        rs_ += __shfl_xor(rs_, 1); rs_ += __shfl_xor(rs_, 2); rs_ += __shfl_xor(rs_, 4);
        if (!(rs_ == rs_)) rs_ = 1e30f;
        const float rmax = blk_reduce_max(rs_, sred, tid);
        if (rmax < 0.3f) break;
        if (attempt == 0) { budget = 3; continue; }
        {
          float rsum = 0.f;
          if (tid < 64)
            for (int u = 0; u < 64; ++u) rsum += fabsf(sQUU[tid * 68 + u]);
          const float s = blk_reduce_max(rsum, sred, tid);
          const float invs = 1.f / s;
          for (int idx = tid; idx < 64 * 68; idx += TPB) {
            const int a2 = idx / 68, b2 = idx - a2 * 68;
            sX[idx] = (a2 == b2) ? invs : 0.f;
          }
          __syncthreads();
          budget = 12;
        }
      }
    }

    float kQk_p = 0.f, kqu_p = 0.f;
    if (tid < 64) {
      const float ka = -dot_f4(&sX[tid * 68], &sq[128], 16);
      sk[tid] = ka;
      out[okOff + (size_t)rrow * 64 + tid] = ka;
    }
    __syncthreads();
    if (tid < 64) {
      const float ta = dot_f4(&sQUU[tid * 68], sk, 16);
      kQk_p = sk[tid] * ta;
      kqu_p = sk[tid] * sq[128 + tid];
    }
    const float kQk = blk_reduce_sum(kQk_p, sred, tid);
    const float kqu = blk_reduce_sum(kqu_p, sred, tid);
    if (tid == 0) {
      const float cstep_ = 0.5f * kQk + kqu + 0.5f * fVf + fv;
      const float dc  = cstep_ - sS[1];
      const float dcp = sS[3];
      sS[3] = dc; sS[1] = cstep_; sS[0] += cstep_;
      out[ocOff + rrow] = sS[0];
      float r = (fabsf(dcp) > 1e-20f) ? dc / dcp : 0.85f;
      if (!(r == r)) r = 0.85f;
      r = fminf(fmaxf(r, -0.85f), 0.85f);
      const float e = -dc * r / (1.f - r);
      sS[5] = r; sS[6] = e;
      sS[7] = (fabsf(e) * (float)T * 0.35f <= 12.f && fabsf(dc) <= 2e-2f) ? 1.f : 0.f;
    }
    __syncthreads();

    {
      const int ag = tid & 3, j = tid >> 2, a0 = ag * 16;
      float w[16] = {0, 0, 0, 0, 0, 0, 0, 0, 0, 0, 0, 0, 0, 0, 0, 0};
      for (int u = 0; u < 64; ++u) {
        const float qx_ = sQXU[j * 68 + u];
        const float4 x0 = *(const float4*)&sX[u * 68 + a0];
        const float4 x1 = *(const float4*)&sX[u * 68 + a0 + 4];
        const float4 x2 = *(const float4*)&sX[u * 68 + a0 + 8];
        const float4 x3 = *(const float4*)&sX[u * 68 + a0 + 12];
        const float xv[16] = {x0.x, x0.y, x0.z, x0.w, x1.x, x1.y, x1.z, x1.w,
                              x2.x, x2.y, x2.z, x2.w, x3.x, x3.y, x3.z, x3.w};
#pragma unroll
        for (int e = 0; e < 16; ++e) w[e] = fmaf(qx_, xv[e], w[e]);
      }
      *(float4*)&sWT[j * 68 + a0]      = make_float4(w[0], w[1], w[2], w[3]);
      *(float4*)&sWT[j * 68 + a0 + 4]  = make_float4(w[4], w[5], w[6], w[7]);
      *(float4*)&sWT[j * 68 + a0 + 8]  = make_float4(w[8], w[9], w[10], w[11]);
      *(float4*)&sWT[j * 68 + a0 + 12] = make_float4(w[12], w[13], w[14], w[15]);
      float* const outK = out + (size_t)rrow * 8192;
#pragma unroll
      for (int e = 0; e < 16; ++e) outK[(a0 + e) * 128 + j] = -w[e];
      __syncthreads();
    }

    {
      const int jg = tid & 3, i = tid >> 2;
      float acc[32];
#pragma unroll
      for (int r = 0; r < 32; ++r) acc[r] = 0.f;
      for (int u4 = 0; u4 < 16; ++u4) {
        const float4 qa = *(const float4*)&sQXU[i * 68 + u4 * 4];
#pragma unroll
        for (int r = 0; r < 32; ++r) {
          const float4 wb = *(const float4*)&sWT[(jg + 4 * r) * 68 + u4 * 4];
          acc[r] += qa.x * wb.x + qa.y * wb.y + qa.z * wb.z + qa.w * wb.w;
        }
      }
      float dmax = 0.f, vmax = 0.f;
#pragma unroll
      for (int r = 0; r < 32; ++r) {
        const int j = jg + 4 * r;
        const float vn_ = outVrow[i * 128 + j] - acc[r];
        dmax = fmaxf(dmax, fabsf(vn_ - sV[i * 132 + j]));
        vmax = fmaxf(vmax, fabsf(vn_));
        sV[i * 132 + j] = vn_;
        outVrow[i * 128 + j] = vn_;
      }
      float dv_p = 0.f, mv_p = 0.f;
      if (tid < 128) {
        float va = sq[tid];
        for (int u = 0; u < 64; ++u) va = fmaf(sQXU[tid * 68 + u], sk[u], va);
        dv_p = fabsf(va - sv[tid]); mv_p = fabsf(va);
        sv[tid] = va;
        out[ovOff + (size_t)rrow * 128 + tid] = va;
      }
      const float dV = blk_reduce_max(dmax, sred, tid);
      const float mV = blk_reduce_max(vmax, sred, tid);
      const float dv = blk_reduce_max(dv_p, sred, tid);
      const float mv = blk_reduce_max(mv_p, sred, tid);
      if (it >= 3 && dV <= 2e-3f * mV && dv <= 4e-3f * fmaxf(1.f, mv) &&
          sS[7] != 0.f) {
        Sdone = it + 1; break;
      }
    }
  }

  if (tid == 0) {
    ((int*)ws)[0] = Sdone;
    ws[1] = sS[1]; ws[2] = sS[0]; ws[3] = sS[5]; ws[4] = sS[6];
  }
}

// ---------------- Kernel B: replicate converged rows + geometric const ----------------
__global__ __launch_bounds__(256) void lqr_fill(
    const float* __restrict__ ws, float* __restrict__ out, int T)
{
  const int S = ((const int*)ws)[0];
  const float cstep = ws[1];
  const float cbase = ws[2];
  const float rho   = ws[3];
  const float e     = ws[4];
  const int r = blockIdx.x;
  const int it = T - 1 - r;
  if (it < S) return;
  const int rs = T - S;
  const int tid = threadIdx.x;
  const size_t okOff = (size_t)T * 8192;
  const size_t oVOff = okOff + (size_t)T * 64;
  const size_t ovOff = oVOff + (size_t)T * 16384;
  const size_t ocOff = ovOff + (size_t)T * 128;

  const float4* __restrict__ sK = (const float4*)(out + (size_t)rs * 8192);
  float4* __restrict__ dK = (float4*)(out + (size_t)r * 8192);
  for (int i = tid; i < 2048; i += 256) dK[i] = sK[i];
  const float4* __restrict__ sVr = (const float4*)(out + oVOff + (size_t)rs * 16384);
  float4* __restrict__ dV = (float4*)(out + oVOff + (size_t)r * 16384);
  for (int i = tid; i < 4096; i += 256) dV[i] = sVr[i];
  if (tid < 16)
    ((float4*)(out + okOff + (size_t)r * 64))[tid] =
        ((const float4*)(out + okOff + (size_t)rs * 64))[tid];
  if (tid >= 32 && tid < 64) {
    const int q = tid - 32;
    ((float4*)(out + ovOff + (size_t)r * 128))[q] =
        ((const float4*)(out + ovOff + (size_t)rs * 128))[q];
  }
  if (tid == 0) {
    const int n = it - (S - 1);
    const float cinf = cstep - e;
    float rp = powf(fabsf(rho), (float)n);
    if (rho < 0.f && (n & 1)) rp = -rp;
    const float geo = (fabsf(1.f - rho) > 1e-6f)
                          ? e * rho * (1.f - rp) / (1.f - rho) : 0.f;
    out[ocOff + r] = cbase + (float)n * cinf + geo;
  }
}

extern "C" void kernel_launch(void* const* d_in, const int* in_sizes, int n_in,
                              void* d_out, int out_size, void* d_ws, size_t ws_size,
                              hipStream_t stream) {
  const float* F = (const float*)d_in[0];
  const float* f = (const float*)d_in[1];
  const float* C = (const float*)d_in[2];
  const float* c = (const float*)d_in[3];
  const int T = out_size / 24769;   // 64*128 + 64 + 128*128 + 128 + 1
  float* out = (float*)d_out;
  float* ws = (float*)d_ws;

  int force = 1;
  if (ws_size >= (size_t)53520 * 4) {
    void* args[] = {(void*)&F, (void*)&f, (void*)&C, (void*)&c,
                    (void*)&out, (void*)&ws, (void*)&T};
    if (hipLaunchCooperativeKernel((void*)lqr_coop, dim3(NWG), dim3(TPB),
                                   args, 0, stream) == hipSuccess)
      force = 0;
  }
  hipLaunchKernelGGL(lqr_fb, dim3(1), dim3(TPB), 0, stream,
                     F, f, C, c, out, ws, T, force);
  hipLaunchKernelGGL(lqr_fill, dim3(T), dim3(256), 0, stream, ws, out, T);
}